// Round 1
// baseline (325.723 us; speedup 1.0000x reference)
//
#include <hip/hip_runtime.h>

// Fused: LayerNorm -> QKV proj -> per-head attention (diag masked) -> out proj
// B=2, N=2048, D=1024, H=16, dh=64. All matmuls via bf16 MFMA 16x16x32.

#define DIMM   1024
#define NSEQ   2048
#define BATCH  2
#define HEADS  16
#define DHEAD  64
#define QKVN   3072
#define MROWS  4096   // BATCH*NSEQ

typedef float          f32x4  __attribute__((ext_vector_type(4)));
typedef __bf16         bf16x8 __attribute__((ext_vector_type(8)));
typedef unsigned short u16x8  __attribute__((ext_vector_type(8)));
typedef unsigned short u16x4  __attribute__((ext_vector_type(4)));

// SCALE * log2(e): fold into q so softmax uses exp2 directly.
#define QSCALE (0.125f * 1.4426950408889634f)

__device__ __forceinline__ unsigned short f2bf(float f) {
  unsigned u = __builtin_bit_cast(unsigned, f);
  u += 0x7FFFu + ((u >> 16) & 1u);   // round-to-nearest-even
  return (unsigned short)(u >> 16);
}
__device__ __forceinline__ bf16x8 as_bf(u16x8 v) { return __builtin_bit_cast(bf16x8, v); }

// ---------------- weight transpose + fp32->bf16 convert: dst[c][r] = src[r][c]
__global__ __launch_bounds__(256) void transpose_bf16_kernel(
    const float* __restrict__ src, unsigned short* __restrict__ dst, int R, int C) {
  __shared__ float t[32][33];
  const int rb = blockIdx.y * 32, cb = blockIdx.x * 32;
  const int r0 = threadIdx.x >> 5;   // 0..7
  const int c  = threadIdx.x & 31;
#pragma unroll
  for (int i = 0; i < 4; ++i)
    t[r0 + i * 8][c] = src[(rb + r0 + i * 8) * C + cb + c];
  __syncthreads();
#pragma unroll
  for (int i = 0; i < 4; ++i)
    dst[(cb + r0 + i * 8) * R + rb + c] = f2bf(t[c][r0 + i * 8]);
}

// ---------------- LayerNorm, one row (1024) per 256-thread block, bf16 out
__global__ __launch_bounds__(256) void ln_kernel(
    const float* __restrict__ x, const float* __restrict__ g,
    const float* __restrict__ be, unsigned short* __restrict__ xn) {
  const int row = blockIdx.x, tid = threadIdx.x;
  const int wave = tid >> 6, lane = tid & 63;
  const float4 v = *(const float4*)&x[row * DIMM + tid * 4];
  float s  = v.x + v.y + v.z + v.w;
  float s2 = v.x * v.x + v.y * v.y + v.z * v.z + v.w * v.w;
#pragma unroll
  for (int o = 32; o >= 1; o >>= 1) { s += __shfl_xor(s, o); s2 += __shfl_xor(s2, o); }
  __shared__ float ps[4], ps2[4];
  if (lane == 0) { ps[wave] = s; ps2[wave] = s2; }
  __syncthreads();
  s  = ps[0] + ps[1] + ps[2] + ps[3];
  s2 = ps2[0] + ps2[1] + ps2[2] + ps2[3];
  const float mu  = s * (1.0f / DIMM);
  const float var = s2 * (1.0f / DIMM) - mu * mu;
  const float rs  = rsqrtf(var + 1e-5f);
  const float4 gg = *(const float4*)&g[tid * 4];
  const float4 bb = *(const float4*)&be[tid * 4];
  u16x4 o;
  o[0] = f2bf((v.x - mu) * rs * gg.x + bb.x);
  o[1] = f2bf((v.y - mu) * rs * gg.y + bb.y);
  o[2] = f2bf((v.z - mu) * rs * gg.z + bb.z);
  o[3] = f2bf((v.w - mu) * rs * gg.w + bb.w);
  *(u16x4*)&xn[row * DIMM + tid * 4] = o;
}

// ---------------- QKV GEMM: [4096,1024] @ wqkvT[3072,1024] -> scatter q/k/vT
// 128x128 block tile, BK=64, 4 waves each 64x64 (4x4 MFMA tiles).
#define BM 128
#define BN 128
#define BK 64
#define LDK 72   // +8 bf16 pad -> 2-way bank aliasing only (free)

__global__ __launch_bounds__(256, 2) void gemm_qkv_kernel(
    const unsigned short* __restrict__ A,   // xn bf16 [4096,1024]
    const unsigned short* __restrict__ Bt,  // wqkvT bf16 [3072,1024]
    unsigned short* __restrict__ qb,        // [bh][n][64], pre-scaled
    unsigned short* __restrict__ kb,        // [bh][n][64]
    unsigned short* __restrict__ vtb) {     // [bh][64][n]
  __shared__ __attribute__((aligned(16))) unsigned short As[BM][LDK];
  __shared__ __attribute__((aligned(16))) unsigned short Bs[BN][LDK];
  const int tid = threadIdx.x;
  const int wave = tid >> 6, lane = tid & 63;
  const int l15 = lane & 15, quad = lane >> 4;
  const int wm = wave >> 1, wn = wave & 1;
  const int bm = blockIdx.y, bn = blockIdx.x;
  const int K = DIMM;
  f32x4 acc[4][4] = {};
  const int srow = tid >> 3;          // 0..31
  const int schunk = (tid & 7) * 8;   // 0..56

  for (int k0 = 0; k0 < K; k0 += BK) {
#pragma unroll
    for (int i = 0; i < 4; ++i) {
      const int r = srow + i * 32;
      *(u16x8*)&As[r][schunk] = *(const u16x8*)&A[(bm * BM + r) * K + k0 + schunk];
      *(u16x8*)&Bs[r][schunk] = *(const u16x8*)&Bt[(bn * BN + r) * K + k0 + schunk];
    }
    __syncthreads();
#pragma unroll
    for (int kk = 0; kk < 2; ++kk) {
      const int co = kk * 32 + quad * 8;
      bf16x8 af[4], bfr[4];
#pragma unroll
      for (int mi = 0; mi < 4; ++mi) af[mi]  = as_bf(*(const u16x8*)&As[wm * 64 + mi * 16 + l15][co]);
#pragma unroll
      for (int ni = 0; ni < 4; ++ni) bfr[ni] = as_bf(*(const u16x8*)&Bs[wn * 64 + ni * 16 + l15][co]);
#pragma unroll
      for (int mi = 0; mi < 4; ++mi)
#pragma unroll
        for (int ni = 0; ni < 4; ++ni)
          acc[mi][ni] = __builtin_amdgcn_mfma_f32_16x16x32_bf16(af[mi], bfr[ni], acc[mi][ni], 0, 0, 0);
    }
    __syncthreads();
  }
  // epilogue: scatter into q (scaled), k, vT
#pragma unroll
  for (int mi = 0; mi < 4; ++mi) {
    const int mrow = bm * BM + wm * 64 + mi * 16 + quad * 4;
#pragma unroll
    for (int ni = 0; ni < 4; ++ni) {
      const int ncol = bn * BN + wn * 64 + ni * 16 + l15;
      const int which = ncol >> 10;   // 0=q 1=k 2=v
      const int idx = ncol & 1023;
      const int h = idx >> 6, dd = idx & 63;
#pragma unroll
      for (int r = 0; r < 4; ++r) {
        const int m = mrow + r;
        const int bidx = m >> 11, n = m & 2047;
        const int bh = bidx * HEADS + h;
        const float v = acc[mi][ni][r];
        if (which == 0)      qb[(bh * NSEQ + n) * DHEAD + dd] = f2bf(v * QSCALE);
        else if (which == 1) kb[(bh * NSEQ + n) * DHEAD + dd] = f2bf(v);
        else                 vtb[(bh * DHEAD + dd) * NSEQ + n] = f2bf(v);
      }
    }
  }
}

// ---------------- flash attention: block = (bh, 64-row q tile), 4 waves x 16 rows
__global__ __launch_bounds__(256, 2) void attn_kernel(
    const unsigned short* __restrict__ qb, const unsigned short* __restrict__ kb,
    const unsigned short* __restrict__ vtb, unsigned short* __restrict__ attn_out) {
  __shared__ __attribute__((aligned(16))) unsigned short Ks[64][72];
  __shared__ __attribute__((aligned(16))) unsigned short Vts[64][72];
  __shared__ __attribute__((aligned(16))) unsigned short Ps[4][16][72];
  const int tid = threadIdx.x, wave = tid >> 6, lane = tid & 63;
  const int l15 = lane & 15, quad = lane >> 4;
  const int bh = blockIdx.x, qt = blockIdx.y;
  const int b = bh >> 4, h = bh & 15;
  const int qbase = qt * 64 + wave * 16;

  // Q fragments for this wave's 16 rows (A-layout: m=lane&15, k=quad*8+j)
  bf16x8 aq[2];
  const unsigned short* qrow = qb + (bh * NSEQ + qbase + l15) * DHEAD;
  aq[0] = as_bf(*(const u16x8*)(qrow + quad * 8));
  aq[1] = as_bf(*(const u16x8*)(qrow + 32 + quad * 8));

  float mstate[4], lstate[4];
  f32x4 occ[4] = {};
#pragma unroll
  for (int r = 0; r < 4; ++r) { mstate[r] = -1e30f; lstate[r] = 0.f; }

  const int srow = tid >> 2;          // 0..63
  const int scol = (tid & 3) * 16;    // 0,16,32,48

  for (int kv = 0; kv < NSEQ; kv += 64) {
    // stage K tile [64][64] and Vt tile [64][64]
    const unsigned short* ksrc = kb + (bh * NSEQ + kv + srow) * DHEAD + scol;
    *(u16x8*)&Ks[srow][scol]     = *(const u16x8*)ksrc;
    *(u16x8*)&Ks[srow][scol + 8] = *(const u16x8*)(ksrc + 8);
    const unsigned short* vsrc = vtb + (bh * DHEAD + srow) * NSEQ + kv + scol;
    *(u16x8*)&Vts[srow][scol]     = *(const u16x8*)vsrc;
    *(u16x8*)&Vts[srow][scol + 8] = *(const u16x8*)(vsrc + 8);
    __syncthreads();

    // S = q' K^T  (q pre-scaled by SCALE*log2e)
    f32x4 scc[4] = {};
#pragma unroll
    for (int kk = 0; kk < 2; ++kk) {
      const int co = kk * 32 + quad * 8;
      const bf16x8 a = aq[kk];
#pragma unroll
      for (int ct = 0; ct < 4; ++ct) {
        bf16x8 bk = as_bf(*(const u16x8*)&Ks[ct * 16 + l15][co]);
        scc[ct] = __builtin_amdgcn_mfma_f32_16x16x32_bf16(a, bk, scc[ct], 0, 0, 0);
      }
    }
    // mask diagonal
#pragma unroll
    for (int ct = 0; ct < 4; ++ct) {
      const int cg = kv + ct * 16 + l15;
#pragma unroll
      for (int r = 0; r < 4; ++r)
        if (cg == qbase + quad * 4 + r) scc[ct][r] = -1e30f;
    }
    // online softmax (rows live on 16 lanes of this quad group)
    float mnew[4], alpha[4];
#pragma unroll
    for (int r = 0; r < 4; ++r) {
      float mx = fmaxf(fmaxf(scc[0][r], scc[1][r]), fmaxf(scc[2][r], scc[3][r]));
      mx = fmaxf(mx, __shfl_xor(mx, 1));
      mx = fmaxf(mx, __shfl_xor(mx, 2));
      mx = fmaxf(mx, __shfl_xor(mx, 4));
      mx = fmaxf(mx, __shfl_xor(mx, 8));
      mnew[r] = fmaxf(mstate[r], mx);
      alpha[r] = exp2f(mstate[r] - mnew[r]);
      mstate[r] = mnew[r];
    }
    float psum[4] = {0.f, 0.f, 0.f, 0.f};
#pragma unroll
    for (int ct = 0; ct < 4; ++ct)
#pragma unroll
      for (int r = 0; r < 4; ++r) {
        const float p = exp2f(scc[ct][r] - mnew[r]);
        scc[ct][r] = p;
        psum[r] += p;
      }
#pragma unroll
    for (int r = 0; r < 4; ++r) {
      float su = psum[r];
      su += __shfl_xor(su, 1);
      su += __shfl_xor(su, 2);
      su += __shfl_xor(su, 4);
      su += __shfl_xor(su, 8);
      lstate[r] = lstate[r] * alpha[r] + su;
    }
#pragma unroll
    for (int ct = 0; ct < 4; ++ct)
#pragma unroll
      for (int r = 0; r < 4; ++r) occ[ct][r] *= alpha[r];

    // P (C-layout) -> LDS -> A-layout
#pragma unroll
    for (int ct = 0; ct < 4; ++ct)
#pragma unroll
      for (int r = 0; r < 4; ++r)
        Ps[wave][quad * 4 + r][ct * 16 + l15] = f2bf(scc[ct][r]);
    __syncthreads();

    // O += P V   (B = Vt: n=d index, k=kv index)
#pragma unroll
    for (int kk = 0; kk < 2; ++kk) {
      const int co = kk * 32 + quad * 8;
      bf16x8 ap = as_bf(*(const u16x8*)&Ps[wave][l15][co]);
#pragma unroll
      for (int ct = 0; ct < 4; ++ct) {
        bf16x8 bv = as_bf(*(const u16x8*)&Vts[ct * 16 + l15][co]);
        occ[ct] = __builtin_amdgcn_mfma_f32_16x16x32_bf16(ap, bv, occ[ct], 0, 0, 0);
      }
    }
    __syncthreads();   // protect Ks/Vts before next staging
  }
  // epilogue: O / l -> attn_out [b*N + n][h*64 + d] bf16
#pragma unroll
  for (int ct = 0; ct < 4; ++ct)
#pragma unroll
    for (int r = 0; r < 4; ++r) {
      const int rg = qbase + quad * 4 + r;
      const float o = occ[ct][r] / lstate[r];
      attn_out[(b * NSEQ + rg) * DIMM + h * DHEAD + ct * 16 + l15] = f2bf(o);
    }
}

// ---------------- output projection: [4096,1024] @ woutT[1024,1024] -> fp32 d_out
__global__ __launch_bounds__(256, 2) void gemm_out_kernel(
    const unsigned short* __restrict__ A,   // attn bf16 [4096,1024]
    const unsigned short* __restrict__ Bt,  // woutT bf16 [1024,1024]
    float* __restrict__ out) {
  __shared__ __attribute__((aligned(16))) unsigned short As[BM][LDK];
  __shared__ __attribute__((aligned(16))) unsigned short Bs[BN][LDK];
  const int tid = threadIdx.x;
  const int wave = tid >> 6, lane = tid & 63;
  const int l15 = lane & 15, quad = lane >> 4;
  const int wm = wave >> 1, wn = wave & 1;
  const int bm = blockIdx.y, bn = blockIdx.x;
  const int K = DIMM;
  f32x4 acc[4][4] = {};
  const int srow = tid >> 3;
  const int schunk = (tid & 7) * 8;

  for (int k0 = 0; k0 < K; k0 += BK) {
#pragma unroll
    for (int i = 0; i < 4; ++i) {
      const int r = srow + i * 32;
      *(u16x8*)&As[r][schunk] = *(const u16x8*)&A[(bm * BM + r) * K + k0 + schunk];
      *(u16x8*)&Bs[r][schunk] = *(const u16x8*)&Bt[(bn * BN + r) * K + k0 + schunk];
    }
    __syncthreads();
#pragma unroll
    for (int kk = 0; kk < 2; ++kk) {
      const int co = kk * 32 + quad * 8;
      bf16x8 af[4], bfr[4];
#pragma unroll
      for (int mi = 0; mi < 4; ++mi) af[mi]  = as_bf(*(const u16x8*)&As[wm * 64 + mi * 16 + l15][co]);
#pragma unroll
      for (int ni = 0; ni < 4; ++ni) bfr[ni] = as_bf(*(const u16x8*)&Bs[wn * 64 + ni * 16 + l15][co]);
#pragma unroll
      for (int mi = 0; mi < 4; ++mi)
#pragma unroll
        for (int ni = 0; ni < 4; ++ni)
          acc[mi][ni] = __builtin_amdgcn_mfma_f32_16x16x32_bf16(af[mi], bfr[ni], acc[mi][ni], 0, 0, 0);
    }
    __syncthreads();
  }
#pragma unroll
  for (int mi = 0; mi < 4; ++mi) {
    const int mrow = bm * BM + wm * 64 + mi * 16 + quad * 4;
#pragma unroll
    for (int ni = 0; ni < 4; ++ni) {
      const int ncol = bn * BN + wn * 64 + ni * 16 + l15;
#pragma unroll
      for (int r = 0; r < 4; ++r)
        out[(mrow + r) * DIMM + ncol] = acc[mi][ni][r];
    }
  }
}

extern "C" void kernel_launch(void* const* d_in, const int* in_sizes, int n_in,
                              void* d_out, int out_size, void* d_ws, size_t ws_size,
                              hipStream_t stream) {
  const float* x     = (const float*)d_in[0];
  const float* gamma = (const float*)d_in[1];
  const float* beta  = (const float*)d_in[2];
  const float* w_qkv = (const float*)d_in[3];  // [1024, 3072]
  const float* w_out = (const float*)d_in[4];  // [1024, 1024]
  float* out = (float*)d_out;

  char* ws = (char*)d_ws;
  unsigned short* xn    = (unsigned short*)(ws);                        // 8 MB
  unsigned short* wqkvT = (unsigned short*)(ws + 8388608);              // 6 MB
  unsigned short* woutT = (unsigned short*)(ws + 14680064);             // 2 MB
  unsigned short* qbuf  = (unsigned short*)(ws + 16777216);             // 8 MB
  unsigned short* kbuf  = (unsigned short*)(ws + 25165824);             // 8 MB
  unsigned short* vtbuf = (unsigned short*)(ws + 33554432);             // 8 MB
  unsigned short* attnb = (unsigned short*)(ws + 41943040);             // 8 MB

  transpose_bf16_kernel<<<dim3(QKVN / 32, DIMM / 32), 256, 0, stream>>>(w_qkv, wqkvT, DIMM, QKVN);
  transpose_bf16_kernel<<<dim3(DIMM / 32, DIMM / 32), 256, 0, stream>>>(w_out, woutT, DIMM, DIMM);
  ln_kernel<<<MROWS, 256, 0, stream>>>(x, gamma, beta, xn);
  gemm_qkv_kernel<<<dim3(QKVN / BN, MROWS / BM), 256, 0, stream>>>(xn, wqkvT, qbuf, kbuf, vtbuf);
  attn_kernel<<<dim3(BATCH * HEADS, NSEQ / 64), 256, 0, stream>>>(qbuf, kbuf, vtbuf, attnb);
  gemm_out_kernel<<<dim3(DIMM / BN, MROWS / BM), 256, 0, stream>>>(attnb, woutT, out);
}

// Round 2
// 225.721 us; speedup vs baseline: 1.4430x; 1.4430x over previous
//
#include <hip/hip_runtime.h>

// Fused: LayerNorm -> QKV proj -> per-head attention (diag masked) -> out proj
// B=2, N=2048, D=1024, H=16, dh=64. bf16 MFMA 16x16x32 everywhere.
// R2: transposed-S attention (per-lane softmax), global_load_lds staging with
//     XOR-swizzled chunks (conflict-free unpadded LDS reads).

#define DIMM   1024
#define NSEQ   2048
#define BATCH  2
#define HEADS  16
#define DHEAD  64
#define QKVN   3072
#define MROWS  4096   // BATCH*NSEQ

typedef float          f32x4  __attribute__((ext_vector_type(4)));
typedef __bf16         bf16x8 __attribute__((ext_vector_type(8)));
typedef unsigned short u16x8  __attribute__((ext_vector_type(8)));
typedef unsigned short u16x4  __attribute__((ext_vector_type(4)));

// SCALE * log2(e): fold into q so softmax uses exp2 directly.
#define QSCALE (0.125f * 1.4426950408889634f)

__device__ __forceinline__ unsigned short f2bf(float f) {
  unsigned u = __builtin_bit_cast(unsigned, f);
  u += 0x7FFFu + ((u >> 16) & 1u);   // round-to-nearest-even
  return (unsigned short)(u >> 16);
}
__device__ __forceinline__ bf16x8 as_bf(u16x8 v) { return __builtin_bit_cast(bf16x8, v); }

// async global->LDS, 16B per lane; LDS dest = wave-uniform base + lane*16
__device__ __forceinline__ void gl_lds16(const unsigned short* g, unsigned short* l) {
  __builtin_amdgcn_global_load_lds(
      (const __attribute__((address_space(1))) unsigned*)g,
      (__attribute__((address_space(3))) unsigned*)l, 16, 0, 0);
}

// swizzled b128 fragment read from an unpadded [rows][64] bf16 tile:
// LDS chunk c at row r holds global chunk c ^ (r&7).
__device__ __forceinline__ bf16x8 lds_frag(const unsigned short* base, int row, int chunk) {
  return as_bf(*(const u16x8*)&base[row * 64 + ((chunk ^ (row & 7)) << 3)]);
}

// ---------------- weight transpose + fp32->bf16 convert: dst[c][r] = src[r][c]
__global__ __launch_bounds__(256) void transpose_bf16_kernel(
    const float* __restrict__ src, unsigned short* __restrict__ dst, int R, int C) {
  __shared__ float t[32][33];
  const int rb = blockIdx.y * 32, cb = blockIdx.x * 32;
  const int r0 = threadIdx.x >> 5;   // 0..7
  const int c  = threadIdx.x & 31;
#pragma unroll
  for (int i = 0; i < 4; ++i)
    t[r0 + i * 8][c] = src[(rb + r0 + i * 8) * C + cb + c];
  __syncthreads();
#pragma unroll
  for (int i = 0; i < 4; ++i)
    dst[(cb + r0 + i * 8) * R + rb + c] = f2bf(t[c][r0 + i * 8]);
}

// ---------------- LayerNorm, one row (1024) per 256-thread block, bf16 out
__global__ __launch_bounds__(256) void ln_kernel(
    const float* __restrict__ x, const float* __restrict__ g,
    const float* __restrict__ be, unsigned short* __restrict__ xn) {
  const int row = blockIdx.x, tid = threadIdx.x;
  const int wave = tid >> 6, lane = tid & 63;
  const float4 v = *(const float4*)&x[row * DIMM + tid * 4];
  float s  = v.x + v.y + v.z + v.w;
  float s2 = v.x * v.x + v.y * v.y + v.z * v.z + v.w * v.w;
#pragma unroll
  for (int o = 32; o >= 1; o >>= 1) { s += __shfl_xor(s, o); s2 += __shfl_xor(s2, o); }
  __shared__ float ps[4], ps2[4];
  if (lane == 0) { ps[wave] = s; ps2[wave] = s2; }
  __syncthreads();
  s  = ps[0] + ps[1] + ps[2] + ps[3];
  s2 = ps2[0] + ps2[1] + ps2[2] + ps2[3];
  const float mu  = s * (1.0f / DIMM);
  const float var = s2 * (1.0f / DIMM) - mu * mu;
  const float rs  = rsqrtf(var + 1e-5f);
  const float4 gg = *(const float4*)&g[tid * 4];
  const float4 bb = *(const float4*)&be[tid * 4];
  u16x4 o;
  o[0] = f2bf((v.x - mu) * rs * gg.x + bb.x);
  o[1] = f2bf((v.y - mu) * rs * gg.y + bb.y);
  o[2] = f2bf((v.z - mu) * rs * gg.z + bb.z);
  o[3] = f2bf((v.w - mu) * rs * gg.w + bb.w);
  *(u16x4*)&xn[row * DIMM + tid * 4] = o;
}

// ---------------- GEMM common: 128x128 tile, BK=64, global_load_lds staging
#define BM 128
#define BN 128
#define BK 64

__global__ __launch_bounds__(256, 2) void gemm_qkv_kernel(
    const unsigned short* __restrict__ A,   // xn bf16 [4096,1024]
    const unsigned short* __restrict__ Bt,  // wqkvT bf16 [3072,1024]
    unsigned short* __restrict__ qb,        // [bh][n][64], pre-scaled
    unsigned short* __restrict__ kb,        // [bh][n][64]
    unsigned short* __restrict__ vtb) {     // [bh][64][n]
  __shared__ __attribute__((aligned(16))) unsigned short As[BM * BK];
  __shared__ __attribute__((aligned(16))) unsigned short Bs[BN * BK];
  const int tid = threadIdx.x;
  const int wave = tid >> 6, lane = tid & 63;
  const int l15 = lane & 15, quad = lane >> 4;
  const int wm = wave >> 1, wn = wave & 1;
  const int bm = blockIdx.y, bn = blockIdx.x;
  f32x4 acc[4][4] = {};
  const int lrow = lane >> 3;                 // 0..7
  const int gcol = ((lane & 7) ^ lrow) << 3;  // swizzled 8-u16 chunk
  const unsigned short* Ab = A  + (bm * BM + wave * 32 + lrow) * DIMM + gcol;
  const unsigned short* Bb = Bt + (bn * BN + wave * 32 + lrow) * DIMM + gcol;

  for (int k0 = 0; k0 < DIMM; k0 += BK) {
#pragma unroll
    for (int j = 0; j < 4; ++j) {
      gl_lds16(Ab + j * 8 * DIMM + k0, &As[(wave * 32 + j * 8) * BK]);
      gl_lds16(Bb + j * 8 * DIMM + k0, &Bs[(wave * 32 + j * 8) * BK]);
    }
    __syncthreads();
#pragma unroll
    for (int kk = 0; kk < 2; ++kk) {
      bf16x8 af[4], bfr[4];
#pragma unroll
      for (int mi = 0; mi < 4; ++mi) af[mi]  = lds_frag(As, wm * 64 + mi * 16 + l15, kk * 4 + quad);
#pragma unroll
      for (int ni = 0; ni < 4; ++ni) bfr[ni] = lds_frag(Bs, wn * 64 + ni * 16 + l15, kk * 4 + quad);
#pragma unroll
      for (int mi = 0; mi < 4; ++mi)
#pragma unroll
        for (int ni = 0; ni < 4; ++ni)
          acc[mi][ni] = __builtin_amdgcn_mfma_f32_16x16x32_bf16(af[mi], bfr[ni], acc[mi][ni], 0, 0, 0);
    }
    __syncthreads();
  }
  // epilogue: scatter into q (scaled), k, vT
#pragma unroll
  for (int mi = 0; mi < 4; ++mi) {
    const int mrow = bm * BM + wm * 64 + mi * 16 + quad * 4;
#pragma unroll
    for (int ni = 0; ni < 4; ++ni) {
      const int ncol = bn * BN + wn * 64 + ni * 16 + l15;
      const int which = ncol >> 10;   // 0=q 1=k 2=v
      const int idx = ncol & 1023;
      const int h = idx >> 6, dd = idx & 63;
#pragma unroll
      for (int r = 0; r < 4; ++r) {
        const int m = mrow + r;
        const int bidx = m >> 11, n = m & 2047;
        const int bh = bidx * HEADS + h;
        const float v = acc[mi][ni][r];
        if (which == 0)      qb[(bh * NSEQ + n) * DHEAD + dd] = f2bf(v * QSCALE);
        else if (which == 1) kb[(bh * NSEQ + n) * DHEAD + dd] = f2bf(v);
        else                 vtb[(bh * DHEAD + dd) * NSEQ + n] = f2bf(v);
      }
    }
  }
}

// ---------------- flash attention, transposed-S form.
// block = (bh, 64-row q tile), 4 waves x 16 q rows; per-lane softmax (q = lane&15).
__global__ __launch_bounds__(256, 2) void attn_kernel(
    const unsigned short* __restrict__ qb, const unsigned short* __restrict__ kb,
    const unsigned short* __restrict__ vtb, unsigned short* __restrict__ attn_out) {
  __shared__ __attribute__((aligned(16))) unsigned short Ks[64 * 64];   // swizzled
  __shared__ __attribute__((aligned(16))) unsigned short Vts[64 * 64];  // swizzled
  __shared__ __attribute__((aligned(16))) unsigned short Ps[4][16][72]; // P[q][kv], per-wave
  const int tid = threadIdx.x, wave = tid >> 6, lane = tid & 63;
  const int l15 = lane & 15, quad = lane >> 4;
  const int bh = blockIdx.x, qt = blockIdx.y;
  const int b = bh >> 4, h = bh & 15;
  const int qg = qt * 64 + wave * 16 + l15;   // this lane's q row (global in seq)

  // Q fragment (B-operand layout: n=lane&15=q, k=quad*8+j), q pre-scaled
  bf16x8 aq[2];
  const unsigned short* qrow = qb + (bh * NSEQ + qg) * DHEAD;
  aq[0] = as_bf(*(const u16x8*)(qrow + quad * 8));
  aq[1] = as_bf(*(const u16x8*)(qrow + 32 + quad * 8));

  float mstate = -1e30f, lstate = 0.f;
  f32x4 occ[4] = {};   // O^T: d = ct*16+quad*4+r, q = l15

  const int lrow = lane >> 3;
  const int gcol = ((lane & 7) ^ lrow) << 3;
  const unsigned short* Kb = kb  + (bh * NSEQ + wave * 16 + lrow) * DHEAD + gcol;
  const unsigned short* Vb = vtb + (bh * DHEAD + wave * 16 + lrow) * NSEQ + gcol;

  for (int kv = 0; kv < NSEQ; kv += 64) {
    // stage K[64][64] and Vt[64][64] via async copy (swizzled chunks)
    gl_lds16(Kb + kv * DHEAD,             &Ks[(wave * 16) * 64]);
    gl_lds16(Kb + kv * DHEAD + 8 * DHEAD, &Ks[(wave * 16 + 8) * 64]);
    gl_lds16(Vb + kv,                     &Vts[(wave * 16) * 64]);
    gl_lds16(Vb + kv + 8 * NSEQ,          &Vts[(wave * 16 + 8) * 64]);
    __syncthreads();

    // S^T = K Q^T : C col=l15=q, row=quad*4+r=kv offset (per ct tile of 16)
    f32x4 scc[4] = {};
#pragma unroll
    for (int kk = 0; kk < 2; ++kk)
#pragma unroll
      for (int ct = 0; ct < 4; ++ct) {
        bf16x8 ak = lds_frag(Ks, ct * 16 + l15, kk * 4 + quad);
        scc[ct] = __builtin_amdgcn_mfma_f32_16x16x32_bf16(ak, aq[kk], scc[ct], 0, 0, 0);
      }

    // per-lane online softmax for row q=l15 (16 scores here; row spans quads)
    float mx = -1e30f;
#pragma unroll
    for (int ct = 0; ct < 4; ++ct)
#pragma unroll
      for (int r = 0; r < 4; ++r) mx = fmaxf(mx, scc[ct][r]);
    mx = fmaxf(mx, __shfl_xor(mx, 16));
    mx = fmaxf(mx, __shfl_xor(mx, 32));
    // mx includes the (masked) diagonal score — still a valid upper bound.
    const float mnew = fmaxf(mstate, mx);
    const float alpha = exp2f(mstate - mnew);
    mstate = mnew;
    float psum = 0.f;
#pragma unroll
    for (int ct = 0; ct < 4; ++ct)
#pragma unroll
      for (int r = 0; r < 4; ++r) {
        float p = exp2f(scc[ct][r] - mnew);
        const int kvg = kv + ct * 16 + quad * 4 + r;
        p = (kvg == qg) ? 0.f : p;   // diagonal mask
        scc[ct][r] = p;
        psum += p;
      }
    psum += __shfl_xor(psum, 16);
    psum += __shfl_xor(psum, 32);
    lstate = lstate * alpha + psum;
#pragma unroll
    for (int ct = 0; ct < 4; ++ct)
#pragma unroll
      for (int r = 0; r < 4; ++r) occ[ct][r] *= alpha;

    // P[q][kv] -> LDS, r-contiguous b64 writes (wave-private slice, no barrier:
    // same-wave LDS ops are processed in order)
#pragma unroll
    for (int ct = 0; ct < 4; ++ct) {
      u16x4 pk;
#pragma unroll
      for (int r = 0; r < 4; ++r) pk[r] = f2bf(scc[ct][r]);
      *(u16x4*)&Ps[wave][l15][ct * 16 + quad * 4] = pk;
    }

    // O^T += V^T P^T : A=Vt (m=d,k=kv), B=P (n=q,k=kv)
#pragma unroll
    for (int kk = 0; kk < 2; ++kk) {
      bf16x8 bp = as_bf(*(const u16x8*)&Ps[wave][l15][kk * 32 + quad * 8]);
#pragma unroll
      for (int ct = 0; ct < 4; ++ct) {
        bf16x8 av = lds_frag(Vts, ct * 16 + l15, kk * 4 + quad);
        occ[ct] = __builtin_amdgcn_mfma_f32_16x16x32_bf16(av, bp, occ[ct], 0, 0, 0);
      }
    }
    __syncthreads();   // all waves done reading Ks/Vts before next staging
  }
  // epilogue: O^T / l -> attn_out[b*N + q][h*64 + d], d-contiguous 8B stores
  const float rl = __builtin_amdgcn_rcpf(lstate);
#pragma unroll
  for (int ct = 0; ct < 4; ++ct) {
    u16x4 ov;
#pragma unroll
    for (int r = 0; r < 4; ++r) ov[r] = f2bf(occ[ct][r] * rl);
    *(u16x4*)&attn_out[(b * NSEQ + qg) * DIMM + h * DHEAD + ct * 16 + quad * 4] = ov;
  }
}

// ---------------- output projection: [4096,1024] @ woutT[1024,1024] -> fp32 d_out
__global__ __launch_bounds__(256, 2) void gemm_out_kernel(
    const unsigned short* __restrict__ A,   // attn bf16 [4096,1024]
    const unsigned short* __restrict__ Bt,  // woutT bf16 [1024,1024]
    float* __restrict__ out) {
  __shared__ __attribute__((aligned(16))) unsigned short As[BM * BK];
  __shared__ __attribute__((aligned(16))) unsigned short Bs[BN * BK];
  const int tid = threadIdx.x;
  const int wave = tid >> 6, lane = tid & 63;
  const int l15 = lane & 15, quad = lane >> 4;
  const int wm = wave >> 1, wn = wave & 1;
  const int bm = blockIdx.y, bn = blockIdx.x;
  f32x4 acc[4][4] = {};
  const int lrow = lane >> 3;
  const int gcol = ((lane & 7) ^ lrow) << 3;
  const unsigned short* Ab = A  + (bm * BM + wave * 32 + lrow) * DIMM + gcol;
  const unsigned short* Bb = Bt + (bn * BN + wave * 32 + lrow) * DIMM + gcol;

  for (int k0 = 0; k0 < DIMM; k0 += BK) {
#pragma unroll
    for (int j = 0; j < 4; ++j) {
      gl_lds16(Ab + j * 8 * DIMM + k0, &As[(wave * 32 + j * 8) * BK]);
      gl_lds16(Bb + j * 8 * DIMM + k0, &Bs[(wave * 32 + j * 8) * BK]);
    }
    __syncthreads();
#pragma unroll
    for (int kk = 0; kk < 2; ++kk) {
      bf16x8 af[4], bfr[4];
#pragma unroll
      for (int mi = 0; mi < 4; ++mi) af[mi]  = lds_frag(As, wm * 64 + mi * 16 + l15, kk * 4 + quad);
#pragma unroll
      for (int ni = 0; ni < 4; ++ni) bfr[ni] = lds_frag(Bs, wn * 64 + ni * 16 + l15, kk * 4 + quad);
#pragma unroll
      for (int mi = 0; mi < 4; ++mi)
#pragma unroll
        for (int ni = 0; ni < 4; ++ni)
          acc[mi][ni] = __builtin_amdgcn_mfma_f32_16x16x32_bf16(af[mi], bfr[ni], acc[mi][ni], 0, 0, 0);
    }
    __syncthreads();
  }
#pragma unroll
  for (int mi = 0; mi < 4; ++mi) {
    const int mrow = bm * BM + wm * 64 + mi * 16 + quad * 4;
#pragma unroll
    for (int ni = 0; ni < 4; ++ni) {
      const int ncol = bn * BN + wn * 64 + ni * 16 + l15;
#pragma unroll
      for (int r = 0; r < 4; ++r)
        out[(mrow + r) * DIMM + ncol] = acc[mi][ni][r];
    }
  }
}

extern "C" void kernel_launch(void* const* d_in, const int* in_sizes, int n_in,
                              void* d_out, int out_size, void* d_ws, size_t ws_size,
                              hipStream_t stream) {
  const float* x     = (const float*)d_in[0];
  const float* gamma = (const float*)d_in[1];
  const float* beta  = (const float*)d_in[2];
  const float* w_qkv = (const float*)d_in[3];  // [1024, 3072]
  const float* w_out = (const float*)d_in[4];  // [1024, 1024]
  float* out = (float*)d_out;

  char* ws = (char*)d_ws;
  unsigned short* xn    = (unsigned short*)(ws);                        // 8 MB
  unsigned short* wqkvT = (unsigned short*)(ws + 8388608);              // 6 MB
  unsigned short* woutT = (unsigned short*)(ws + 14680064);             // 2 MB
  unsigned short* qbuf  = (unsigned short*)(ws + 16777216);             // 8 MB
  unsigned short* kbuf  = (unsigned short*)(ws + 25165824);             // 8 MB
  unsigned short* vtbuf = (unsigned short*)(ws + 33554432);             // 8 MB
  unsigned short* attnb = (unsigned short*)(ws + 41943040);             // 8 MB

  transpose_bf16_kernel<<<dim3(QKVN / 32, DIMM / 32), 256, 0, stream>>>(w_qkv, wqkvT, DIMM, QKVN);
  transpose_bf16_kernel<<<dim3(DIMM / 32, DIMM / 32), 256, 0, stream>>>(w_out, woutT, DIMM, DIMM);
  ln_kernel<<<MROWS, 256, 0, stream>>>(x, gamma, beta, xn);
  gemm_qkv_kernel<<<dim3(QKVN / BN, MROWS / BM), 256, 0, stream>>>(xn, wqkvT, qbuf, kbuf, vtbuf);
  attn_kernel<<<dim3(BATCH * HEADS, NSEQ / 64), 256, 0, stream>>>(qbuf, kbuf, vtbuf, attnb);
  gemm_out_kernel<<<dim3(DIMM / BN, MROWS / BM), 256, 0, stream>>>(attnb, woutT, out);
}

// Round 3
// 203.193 us; speedup vs baseline: 1.6030x; 1.1109x over previous
//
#include <hip/hip_runtime.h>

// Fused: LayerNorm -> QKV proj -> per-head attention (diag masked) -> out proj
// B=2, N=2048, D=1024, H=16, dh=64. bf16 MFMA 16x16x32 everywhere.
// R3: fixed-offset softmax (no online max: scores bounded, -32 folded into MFMA
//     C-init), block-uniform diagonal mask, native bf16 converts, and
//     orientation-split QKV epilogue (C^T for q/k blocks, C for v blocks) so
//     all stores are b64.

#define DIMM   1024
#define NSEQ   2048
#define BATCH  2
#define HEADS  16
#define DHEAD  64
#define QKVN   3072
#define MROWS  4096   // BATCH*NSEQ

typedef float          f32x4  __attribute__((ext_vector_type(4)));
typedef __bf16         bf16x8 __attribute__((ext_vector_type(8)));
typedef __bf16         bf16x4 __attribute__((ext_vector_type(4)));
typedef unsigned short u16x8  __attribute__((ext_vector_type(8)));
typedef unsigned short u16x4  __attribute__((ext_vector_type(4)));

// SCALE * log2(e): fold into q so softmax uses exp2 directly.
#define QSCALE (0.125f * 1.4426950408889634f)

#if __has_builtin(__builtin_amdgcn_exp2f)
#define EXP2(x) __builtin_amdgcn_exp2f(x)
#else
#define EXP2(x) exp2f(x)
#endif

__device__ __forceinline__ unsigned short f2bf(float f) {
  unsigned u = __builtin_bit_cast(unsigned, f);
  u += 0x7FFFu + ((u >> 16) & 1u);   // round-to-nearest-even
  return (unsigned short)(u >> 16);
}
__device__ __forceinline__ bf16x8 as_bf(u16x8 v) { return __builtin_bit_cast(bf16x8, v); }

// f32x4 -> 4 bf16 (RNE); backend selects v_cvt_pk_bf16_f32 on gfx950.
__device__ __forceinline__ u16x4 cvt4(f32x4 v) {
  bf16x4 b;
  b[0] = (__bf16)v[0]; b[1] = (__bf16)v[1]; b[2] = (__bf16)v[2]; b[3] = (__bf16)v[3];
  return __builtin_bit_cast(u16x4, b);
}

// async global->LDS, 16B per lane; LDS dest = wave-uniform base + lane*16
__device__ __forceinline__ void gl_lds16(const unsigned short* g, unsigned short* l) {
  __builtin_amdgcn_global_load_lds(
      (const __attribute__((address_space(1))) unsigned*)g,
      (__attribute__((address_space(3))) unsigned*)l, 16, 0, 0);
}

// swizzled b128 fragment read from an unpadded [rows][64] bf16 tile:
// LDS chunk c at row r holds global chunk c ^ (r&7).
__device__ __forceinline__ bf16x8 lds_frag(const unsigned short* base, int row, int chunk) {
  return as_bf(*(const u16x8*)&base[row * 64 + ((chunk ^ (row & 7)) << 3)]);
}

// ---------------- weight transpose + fp32->bf16 convert: dst[c][r] = src[r][c]
__global__ __launch_bounds__(256) void transpose_bf16_kernel(
    const float* __restrict__ src, unsigned short* __restrict__ dst, int R, int C) {
  __shared__ float t[32][33];
  const int rb = blockIdx.y * 32, cb = blockIdx.x * 32;
  const int r0 = threadIdx.x >> 5;   // 0..7
  const int c  = threadIdx.x & 31;
#pragma unroll
  for (int i = 0; i < 4; ++i)
    t[r0 + i * 8][c] = src[(rb + r0 + i * 8) * C + cb + c];
  __syncthreads();
#pragma unroll
  for (int i = 0; i < 4; ++i)
    dst[(cb + r0 + i * 8) * R + rb + c] = f2bf(t[c][r0 + i * 8]);
}

// ---------------- LayerNorm, one row (1024) per 256-thread block, bf16 out
__global__ __launch_bounds__(256) void ln_kernel(
    const float* __restrict__ x, const float* __restrict__ g,
    const float* __restrict__ be, unsigned short* __restrict__ xn) {
  const int row = blockIdx.x, tid = threadIdx.x;
  const int wave = tid >> 6, lane = tid & 63;
  const float4 v = *(const float4*)&x[row * DIMM + tid * 4];
  float s  = v.x + v.y + v.z + v.w;
  float s2 = v.x * v.x + v.y * v.y + v.z * v.z + v.w * v.w;
#pragma unroll
  for (int o = 32; o >= 1; o >>= 1) { s += __shfl_xor(s, o); s2 += __shfl_xor(s2, o); }
  __shared__ float ps[4], ps2[4];
  if (lane == 0) { ps[wave] = s; ps2[wave] = s2; }
  __syncthreads();
  s  = ps[0] + ps[1] + ps[2] + ps[3];
  s2 = ps2[0] + ps2[1] + ps2[2] + ps2[3];
  const float mu  = s * (1.0f / DIMM);
  const float var = s2 * (1.0f / DIMM) - mu * mu;
  const float rs  = rsqrtf(var + 1e-5f);
  const float4 gg = *(const float4*)&g[tid * 4];
  const float4 bb = *(const float4*)&be[tid * 4];
  u16x4 o;
  o[0] = f2bf((v.x - mu) * rs * gg.x + bb.x);
  o[1] = f2bf((v.y - mu) * rs * gg.y + bb.y);
  o[2] = f2bf((v.z - mu) * rs * gg.z + bb.z);
  o[3] = f2bf((v.w - mu) * rs * gg.w + bb.w);
  *(u16x4*)&xn[row * DIMM + tid * 4] = o;
}

// ---------------- GEMM core: 128x128 tile, BK=64, global_load_lds staging.
// SWAP=true computes C^T (operands exchanged; A/B frag layouts are identical).
template<bool SWAP>
__device__ __forceinline__ void gemm_core128(
    const unsigned short* __restrict__ A, const unsigned short* __restrict__ Bt,
    unsigned short* As, unsigned short* Bs, int bm, int bn, int tid,
    f32x4 (&acc)[4][4]) {
  const int wave = tid >> 6, lane = tid & 63;
  const int l15 = lane & 15, quad = lane >> 4;
  const int wm = wave >> 1, wn = wave & 1;
  const int lrow = lane >> 3;                 // 0..7
  const int gcol = ((lane & 7) ^ lrow) << 3;  // swizzled 8-u16 chunk
  const unsigned short* Ab = A  + (bm * 128 + wave * 32 + lrow) * DIMM + gcol;
  const unsigned short* Bb = Bt + (bn * 128 + wave * 32 + lrow) * DIMM + gcol;

  for (int k0 = 0; k0 < DIMM; k0 += 64) {
#pragma unroll
    for (int j = 0; j < 4; ++j) {
      gl_lds16(Ab + j * 8 * DIMM + k0, &As[(wave * 32 + j * 8) * 64]);
      gl_lds16(Bb + j * 8 * DIMM + k0, &Bs[(wave * 32 + j * 8) * 64]);
    }
    __syncthreads();
#pragma unroll
    for (int kk = 0; kk < 2; ++kk) {
      bf16x8 af[4], bfr[4];
#pragma unroll
      for (int mi = 0; mi < 4; ++mi) af[mi]  = lds_frag(As, wm * 64 + mi * 16 + l15, kk * 4 + quad);
#pragma unroll
      for (int ni = 0; ni < 4; ++ni) bfr[ni] = lds_frag(Bs, wn * 64 + ni * 16 + l15, kk * 4 + quad);
#pragma unroll
      for (int mi = 0; mi < 4; ++mi)
#pragma unroll
        for (int ni = 0; ni < 4; ++ni)
          acc[mi][ni] = SWAP
            ? __builtin_amdgcn_mfma_f32_16x16x32_bf16(bfr[ni], af[mi], acc[mi][ni], 0, 0, 0)
            : __builtin_amdgcn_mfma_f32_16x16x32_bf16(af[mi], bfr[ni], acc[mi][ni], 0, 0, 0);
    }
    __syncthreads();
  }
}

// q/k blocks (bn 0..15): C^T form -> reg r runs along weight col (dd) -> b64 stores.
__global__ __launch_bounds__(256, 2) void gemm_qk_kernel(
    const unsigned short* __restrict__ A, const unsigned short* __restrict__ Bt,
    unsigned short* __restrict__ qb, unsigned short* __restrict__ kb) {
  __shared__ __attribute__((aligned(16))) unsigned short As[128 * 64];
  __shared__ __attribute__((aligned(16))) unsigned short Bs[128 * 64];
  const int tid = threadIdx.x;
  const int bm = blockIdx.y, bn = blockIdx.x;
  f32x4 acc[4][4] = {};
  gemm_core128<true>(A, Bt, As, Bs, bm, bn, tid, acc);

  const int lane = tid & 63, wave = tid >> 6;
  const int l15 = lane & 15, quad = lane >> 4;
  const int wm = wave >> 1, wn = wave & 1;
  const int colbase = bn * 128 + wn * 64;        // wave-uniform
  const int which = colbase >> 10;               // 0=q, 1=k
  unsigned short* dst = which ? kb : qb;
  const float sc = which ? 1.0f : QSCALE;
#pragma unroll
  for (int mi = 0; mi < 4; ++mi) {
    const int m = bm * 128 + wm * 64 + mi * 16 + l15;   // xn row
    const int bh0 = (m >> 11) * HEADS;
    const int n = m & 2047;
#pragma unroll
    for (int ni = 0; ni < 4; ++ni) {
      const int wc = (colbase & 1023) + ni * 16 + quad * 4;  // q/k col, r-contig
      const int h = wc >> 6, dd = wc & 63;
      f32x4 v = acc[mi][ni] * sc;
      *(u16x4*)&dst[((bh0 + h) * NSEQ + n) * DHEAD + dd] = cvt4(v);
    }
  }
}

// v blocks (bn 16..23): original form -> reg r runs along n -> b64 stores to vt.
__global__ __launch_bounds__(256, 2) void gemm_v_kernel(
    const unsigned short* __restrict__ A, const unsigned short* __restrict__ Bt,
    unsigned short* __restrict__ vtb) {
  __shared__ __attribute__((aligned(16))) unsigned short As[128 * 64];
  __shared__ __attribute__((aligned(16))) unsigned short Bs[128 * 64];
  const int tid = threadIdx.x;
  const int bm = blockIdx.y, bn = blockIdx.x + 16;
  f32x4 acc[4][4] = {};
  gemm_core128<false>(A, Bt, As, Bs, bm, bn, tid, acc);

  const int lane = tid & 63, wave = tid >> 6;
  const int l15 = lane & 15, quad = lane >> 4;
  const int wm = wave >> 1, wn = wave & 1;
  const int colbase = bn * 128 + wn * 64 - 2048;   // v col base, 0..1023
#pragma unroll
  for (int mi = 0; mi < 4; ++mi) {
    const int m0 = bm * 128 + wm * 64 + mi * 16 + quad * 4;   // n, r-contig
    const int bh0 = (m0 >> 11) * HEADS;
    const int n0 = m0 & 2047;
#pragma unroll
    for (int ni = 0; ni < 4; ++ni) {
      const int vcol = colbase + ni * 16 + l15;
      const int h = vcol >> 6, dd = vcol & 63;
      *(u16x4*)&vtb[((bh0 + h) * DHEAD + dd) * NSEQ + n0] = cvt4(acc[mi][ni]);
    }
  }
}

// ---------------- flash attention, transposed-S, fixed-offset softmax.
// block = (bh, 64-row q tile), 4 waves x 16 q rows; per-lane softmax (q = lane&15).
// p = exp2(s - 32); numerator/denominator share the 2^-32 scale (cancels).
__global__ __launch_bounds__(256, 2) void attn_kernel(
    const unsigned short* __restrict__ qb, const unsigned short* __restrict__ kb,
    const unsigned short* __restrict__ vtb, unsigned short* __restrict__ attn_out) {
  __shared__ __attribute__((aligned(16))) unsigned short Ks[64 * 64];   // swizzled
  __shared__ __attribute__((aligned(16))) unsigned short Vts[64 * 64];  // swizzled
  __shared__ __attribute__((aligned(16))) unsigned short Ps[4][16][72]; // P[q][kv], per-wave
  const int tid = threadIdx.x, wave = tid >> 6, lane = tid & 63;
  const int l15 = lane & 15, quad = lane >> 4;
  const int bh = blockIdx.x, qt = blockIdx.y;
  const int b = bh >> 4, h = bh & 15;
  const int qt64 = qt * 64;
  const int qg = qt64 + wave * 16 + l15;   // this lane's q row (global in seq)

  // Q fragment (B-operand layout: n=lane&15=q, k=quad*8+j), q pre-scaled
  bf16x8 aq[2];
  const unsigned short* qrow = qb + (bh * NSEQ + qg) * DHEAD;
  aq[0] = as_bf(*(const u16x8*)(qrow + quad * 8));
  aq[1] = as_bf(*(const u16x8*)(qrow + 32 + quad * 8));

  float lsum = 0.f;
  f32x4 occ[4] = {};   // O^T: d = ct*16+quad*4+r, q = l15

  const int lrow = lane >> 3;
  const int gcol = ((lane & 7) ^ lrow) << 3;
  const unsigned short* Kb = kb  + (bh * NSEQ + wave * 16 + lrow) * DHEAD + gcol;
  const unsigned short* Vb = vtb + (bh * DHEAD + wave * 16 + lrow) * NSEQ + gcol;

  for (int kv = 0; kv < NSEQ; kv += 64) {
    // stage K[64][64] and Vt[64][64] via async copy (swizzled chunks)
    gl_lds16(Kb + kv * DHEAD,             &Ks[(wave * 16) * 64]);
    gl_lds16(Kb + kv * DHEAD + 8 * DHEAD, &Ks[(wave * 16 + 8) * 64]);
    gl_lds16(Vb + kv,                     &Vts[(wave * 16) * 64]);
    gl_lds16(Vb + kv + 8 * NSEQ,          &Vts[(wave * 16 + 8) * 64]);
    __syncthreads();

    // S^T - 32 = K Q^T - 32 : col=l15=q, row=quad*4+r=kv offset (per ct tile)
    f32x4 scc[4];
#pragma unroll
    for (int ct = 0; ct < 4; ++ct) scc[ct] = (f32x4){-32.f, -32.f, -32.f, -32.f};
#pragma unroll
    for (int kk = 0; kk < 2; ++kk)
#pragma unroll
      for (int ct = 0; ct < 4; ++ct) {
        bf16x8 ak = lds_frag(Ks, ct * 16 + l15, kk * 4 + quad);
        scc[ct] = __builtin_amdgcn_mfma_f32_16x16x32_bf16(ak, aq[kk], scc[ct], 0, 0, 0);
      }

    // p = exp2(s - 32); no per-tile max needed (s bounded << 32)
#pragma unroll
    for (int ct = 0; ct < 4; ++ct)
#pragma unroll
      for (int r = 0; r < 4; ++r) scc[ct][r] = EXP2(scc[ct][r]);

    // diagonal mask: only the kv tile aligned with this block's q tile
    // (block-uniform branch, 1 of 32 iters). Zero BEFORE summing.
    if (kv == qt64) {
#pragma unroll
      for (int ct = 0; ct < 4; ++ct)
#pragma unroll
        for (int r = 0; r < 4; ++r) {
          const int kvo = ct * 16 + quad * 4 + r;
          if (kvo == wave * 16 + l15) scc[ct][r] = 0.f;
        }
    }

    f32x4 ps4 = (scc[0] + scc[1]) + (scc[2] + scc[3]);
    lsum += (ps4[0] + ps4[1]) + (ps4[2] + ps4[3]);

    // P[q][kv] -> LDS, r-contiguous b64 writes (wave-private slice, in-order)
#pragma unroll
    for (int ct = 0; ct < 4; ++ct)
      *(u16x4*)&Ps[wave][l15][ct * 16 + quad * 4] = cvt4(scc[ct]);

    // O^T += V^T P^T : A=Vt (m=d,k=kv), B=P (n=q,k=kv)
#pragma unroll
    for (int kk = 0; kk < 2; ++kk) {
      bf16x8 bp = as_bf(*(const u16x8*)&Ps[wave][l15][kk * 32 + quad * 8]);
#pragma unroll
      for (int ct = 0; ct < 4; ++ct) {
        bf16x8 av = lds_frag(Vts, ct * 16 + l15, kk * 4 + quad);
        occ[ct] = __builtin_amdgcn_mfma_f32_16x16x32_bf16(av, bp, occ[ct], 0, 0, 0);
      }
    }
    __syncthreads();   // all waves done reading Ks/Vts before next staging
  }
  // row sum spans the 4 quads
  lsum += __shfl_xor(lsum, 16);
  lsum += __shfl_xor(lsum, 32);
  const float rl = __builtin_amdgcn_rcpf(lsum);
  // epilogue: O^T / l -> attn_out[b*N + q][h*64 + d], d-contiguous 8B stores
#pragma unroll
  for (int ct = 0; ct < 4; ++ct) {
    f32x4 ov = occ[ct] * rl;
    *(u16x4*)&attn_out[(b * NSEQ + qg) * DIMM + h * DHEAD + ct * 16 + quad * 4] = cvt4(ov);
  }
}

// ---------------- output projection: [4096,1024] @ woutT[1024,1024] -> fp32 d_out
__global__ __launch_bounds__(256, 2) void gemm_out_kernel(
    const unsigned short* __restrict__ A,   // attn bf16 [4096,1024]
    const unsigned short* __restrict__ Bt,  // woutT bf16 [1024,1024]
    float* __restrict__ out) {
  __shared__ __attribute__((aligned(16))) unsigned short As[128 * 64];
  __shared__ __attribute__((aligned(16))) unsigned short Bs[128 * 64];
  const int tid = threadIdx.x;
  const int bm = blockIdx.y, bn = blockIdx.x;
  f32x4 acc[4][4] = {};
  gemm_core128<false>(A, Bt, As, Bs, bm, bn, tid, acc);

  const int lane = tid & 63, wave = tid >> 6;
  const int l15 = lane & 15, quad = lane >> 4;
  const int wm = wave >> 1, wn = wave & 1;
#pragma unroll
  for (int mi = 0; mi < 4; ++mi) {
    const int mrow = bm * 128 + wm * 64 + mi * 16 + quad * 4;
#pragma unroll
    for (int ni = 0; ni < 4; ++ni) {
      const int ncol = bn * 128 + wn * 64 + ni * 16 + l15;
#pragma unroll
      for (int r = 0; r < 4; ++r)
        out[(mrow + r) * DIMM + ncol] = acc[mi][ni][r];
    }
  }
}

extern "C" void kernel_launch(void* const* d_in, const int* in_sizes, int n_in,
                              void* d_out, int out_size, void* d_ws, size_t ws_size,
                              hipStream_t stream) {
  const float* x     = (const float*)d_in[0];
  const float* gamma = (const float*)d_in[1];
  const float* beta  = (const float*)d_in[2];
  const float* w_qkv = (const float*)d_in[3];  // [1024, 3072]
  const float* w_out = (const float*)d_in[4];  // [1024, 1024]
  float* out = (float*)d_out;

  char* ws = (char*)d_ws;
  unsigned short* xn    = (unsigned short*)(ws);                        // 8 MB
  unsigned short* wqkvT = (unsigned short*)(ws + 8388608);              // 6 MB
  unsigned short* woutT = (unsigned short*)(ws + 14680064);             // 2 MB
  unsigned short* qbuf  = (unsigned short*)(ws + 16777216);             // 8 MB
  unsigned short* kbuf  = (unsigned short*)(ws + 25165824);             // 8 MB
  unsigned short* vtbuf = (unsigned short*)(ws + 33554432);             // 8 MB
  unsigned short* attnb = (unsigned short*)(ws + 41943040);             // 8 MB

  transpose_bf16_kernel<<<dim3(QKVN / 32, DIMM / 32), 256, 0, stream>>>(w_qkv, wqkvT, DIMM, QKVN);
  transpose_bf16_kernel<<<dim3(DIMM / 32, DIMM / 32), 256, 0, stream>>>(w_out, woutT, DIMM, DIMM);
  ln_kernel<<<MROWS, 256, 0, stream>>>(x, gamma, beta, xn);
  gemm_qk_kernel<<<dim3(16, MROWS / 128), 256, 0, stream>>>(xn, wqkvT, qbuf, kbuf);
  gemm_v_kernel<<<dim3(8, MROWS / 128), 256, 0, stream>>>(xn, wqkvT, vtbuf);
  attn_kernel<<<dim3(BATCH * HEADS, NSEQ / 64), 256, 0, stream>>>(qbuf, kbuf, vtbuf, attnb);
  gemm_out_kernel<<<dim3(DIMM / 128, MROWS / 128), 256, 0, stream>>>(attnb, woutT, out);
}

// Round 4
// 189.281 us; speedup vs baseline: 1.7208x; 1.0735x over previous
//
#include <hip/hip_runtime.h>

// Fused: LayerNorm -> QKV proj -> per-head attention (diag masked) -> out proj
// B=2, N=2048, D=1024, H=16, dh=64. bf16 MFMA 16x16x32 everywhere.
// R4: attention with 128-q tiles, double-buffered K/V staging and ONE barrier
//     per kv-iter (async loads overlap compute); hoisted K/V fragments reused
//     by 2 q-subtiles; C^T-oriented out-proj (dwordx4 stores); merged
//     transpose kernel and merged QKV gemm (5 launches total).

#define DIMM   1024
#define NSEQ   2048
#define BATCH  2
#define HEADS  16
#define DHEAD  64
#define QKVN   3072
#define MROWS  4096   // BATCH*NSEQ

typedef float          f32x4  __attribute__((ext_vector_type(4)));
typedef __bf16         bf16x8 __attribute__((ext_vector_type(8)));
typedef __bf16         bf16x4 __attribute__((ext_vector_type(4)));
typedef unsigned short u16x8  __attribute__((ext_vector_type(8)));
typedef unsigned short u16x4  __attribute__((ext_vector_type(4)));

// SCALE * log2(e): fold into q so softmax uses exp2 directly.
#define QSCALE (0.125f * 1.4426950408889634f)

#if __has_builtin(__builtin_amdgcn_exp2f)
#define EXP2(x) __builtin_amdgcn_exp2f(x)
#else
#define EXP2(x) exp2f(x)
#endif

__device__ __forceinline__ unsigned short f2bf(float f) {
  unsigned u = __builtin_bit_cast(unsigned, f);
  u += 0x7FFFu + ((u >> 16) & 1u);   // round-to-nearest-even
  return (unsigned short)(u >> 16);
}
__device__ __forceinline__ bf16x8 as_bf(u16x8 v) { return __builtin_bit_cast(bf16x8, v); }

// f32x4 -> 4 bf16 (RNE)
__device__ __forceinline__ u16x4 cvt4(f32x4 v) {
  bf16x4 b;
  b[0] = (__bf16)v[0]; b[1] = (__bf16)v[1]; b[2] = (__bf16)v[2]; b[3] = (__bf16)v[3];
  return __builtin_bit_cast(u16x4, b);
}

// async global->LDS, 16B per lane; LDS dest = wave-uniform base + lane*16
__device__ __forceinline__ void gl_lds16(const unsigned short* g, unsigned short* l) {
  __builtin_amdgcn_global_load_lds(
      (const __attribute__((address_space(1))) unsigned*)g,
      (__attribute__((address_space(3))) unsigned*)l, 16, 0, 0);
}

// swizzled b128 fragment read from an unpadded [rows][64] bf16 tile:
// LDS chunk c at row r holds global chunk c ^ (r&7).
__device__ __forceinline__ bf16x8 lds_frag(const unsigned short* base, int row, int chunk) {
  return as_bf(*(const u16x8*)&base[row * 64 + ((chunk ^ (row & 7)) << 3)]);
}

// ---------------- merged weight transpose + fp32->bf16: dst[c][r] = src[r][c]
__device__ __forceinline__ void transpose_tile(
    const float* __restrict__ src, unsigned short* __restrict__ dst,
    int R, int C, int bx, int by, int tid) {
  __shared__ float t[32][33];
  const int rb = by * 32, cb = bx * 32;
  const int r0 = tid >> 5;   // 0..7
  const int c  = tid & 31;
#pragma unroll
  for (int i = 0; i < 4; ++i)
    t[r0 + i * 8][c] = src[(rb + r0 + i * 8) * C + cb + c];
  __syncthreads();
#pragma unroll
  for (int i = 0; i < 4; ++i)
    dst[(cb + r0 + i * 8) * R + rb + c] = f2bf(t[c][r0 + i * 8]);
}

__global__ __launch_bounds__(256) void transpose2_kernel(
    const float* __restrict__ w_qkv, const float* __restrict__ w_out,
    unsigned short* __restrict__ wqkvT, unsigned short* __restrict__ woutT) {
  const int bx = blockIdx.x;
  if (bx < QKVN / 32) transpose_tile(w_qkv, wqkvT, DIMM, QKVN, bx, blockIdx.y, threadIdx.x);
  else                transpose_tile(w_out, woutT, DIMM, DIMM, bx - QKVN / 32, blockIdx.y, threadIdx.x);
}

// ---------------- LayerNorm, one row (1024) per 256-thread block, bf16 out
__global__ __launch_bounds__(256) void ln_kernel(
    const float* __restrict__ x, const float* __restrict__ g,
    const float* __restrict__ be, unsigned short* __restrict__ xn) {
  const int row = blockIdx.x, tid = threadIdx.x;
  const int wave = tid >> 6, lane = tid & 63;
  const float4 v = *(const float4*)&x[row * DIMM + tid * 4];
  float s  = v.x + v.y + v.z + v.w;
  float s2 = v.x * v.x + v.y * v.y + v.z * v.z + v.w * v.w;
#pragma unroll
  for (int o = 32; o >= 1; o >>= 1) { s += __shfl_xor(s, o); s2 += __shfl_xor(s2, o); }
  __shared__ float ps[4], ps2[4];
  if (lane == 0) { ps[wave] = s; ps2[wave] = s2; }
  __syncthreads();
  s  = ps[0] + ps[1] + ps[2] + ps[3];
  s2 = ps2[0] + ps2[1] + ps2[2] + ps2[3];
  const float mu  = s * (1.0f / DIMM);
  const float var = s2 * (1.0f / DIMM) - mu * mu;
  const float rs  = rsqrtf(var + 1e-5f);
  const float4 gg = *(const float4*)&g[tid * 4];
  const float4 bb = *(const float4*)&be[tid * 4];
  u16x4 o;
  o[0] = f2bf((v.x - mu) * rs * gg.x + bb.x);
  o[1] = f2bf((v.y - mu) * rs * gg.y + bb.y);
  o[2] = f2bf((v.z - mu) * rs * gg.z + bb.z);
  o[3] = f2bf((v.w - mu) * rs * gg.w + bb.w);
  *(u16x4*)&xn[row * DIMM + tid * 4] = o;
}

// ---------------- GEMM core: 128x128 tile, BK=64, global_load_lds staging.
// SWAP=true computes C^T (operands exchanged; A/B frag layouts are identical).
template<bool SWAP>
__device__ __forceinline__ void gemm_core128(
    const unsigned short* __restrict__ A, const unsigned short* __restrict__ Bt,
    unsigned short* As, unsigned short* Bs, int bm, int bn, int tid,
    f32x4 (&acc)[4][4]) {
  const int wave = tid >> 6, lane = tid & 63;
  const int l15 = lane & 15, quad = lane >> 4;
  const int wm = wave >> 1, wn = wave & 1;
  const int lrow = lane >> 3;                 // 0..7
  const int gcol = ((lane & 7) ^ lrow) << 3;  // swizzled 8-u16 chunk
  const unsigned short* Ab = A  + (bm * 128 + wave * 32 + lrow) * DIMM + gcol;
  const unsigned short* Bb = Bt + (bn * 128 + wave * 32 + lrow) * DIMM + gcol;

  for (int k0 = 0; k0 < DIMM; k0 += 64) {
#pragma unroll
    for (int j = 0; j < 4; ++j) {
      gl_lds16(Ab + j * 8 * DIMM + k0, &As[(wave * 32 + j * 8) * 64]);
      gl_lds16(Bb + j * 8 * DIMM + k0, &Bs[(wave * 32 + j * 8) * 64]);
    }
    __syncthreads();
#pragma unroll
    for (int kk = 0; kk < 2; ++kk) {
      bf16x8 af[4], bfr[4];
#pragma unroll
      for (int mi = 0; mi < 4; ++mi) af[mi]  = lds_frag(As, wm * 64 + mi * 16 + l15, kk * 4 + quad);
#pragma unroll
      for (int ni = 0; ni < 4; ++ni) bfr[ni] = lds_frag(Bs, wn * 64 + ni * 16 + l15, kk * 4 + quad);
#pragma unroll
      for (int mi = 0; mi < 4; ++mi)
#pragma unroll
        for (int ni = 0; ni < 4; ++ni)
          acc[mi][ni] = SWAP
            ? __builtin_amdgcn_mfma_f32_16x16x32_bf16(bfr[ni], af[mi], acc[mi][ni], 0, 0, 0)
            : __builtin_amdgcn_mfma_f32_16x16x32_bf16(af[mi], bfr[ni], acc[mi][ni], 0, 0, 0);
    }
    __syncthreads();
  }
}

// ---------------- merged QKV GEMM: bn 0..15 -> q/k (C^T), bn 16..23 -> v (C)
__global__ __launch_bounds__(256, 2) void gemm_qkv_kernel(
    const unsigned short* __restrict__ A, const unsigned short* __restrict__ Bt,
    unsigned short* __restrict__ qb, unsigned short* __restrict__ kb,
    unsigned short* __restrict__ vtb) {
  __shared__ __attribute__((aligned(16))) unsigned short As[128 * 64];
  __shared__ __attribute__((aligned(16))) unsigned short Bs[128 * 64];
  const int tid = threadIdx.x;
  const int bm = blockIdx.y, bn = blockIdx.x;
  const int lane = tid & 63, wave = tid >> 6;
  const int l15 = lane & 15, quad = lane >> 4;
  const int wm = wave >> 1, wn = wave & 1;
  f32x4 acc[4][4] = {};

  if (bn < 16) {
    // q/k blocks: C^T form -> reg r runs along weight col (dd) -> b64 stores.
    gemm_core128<true>(A, Bt, As, Bs, bm, bn, tid, acc);
    const int colbase = bn * 128 + wn * 64;        // wave-uniform
    const int which = colbase >> 10;               // 0=q, 1=k
    unsigned short* dst = which ? kb : qb;
    const float sc = which ? 1.0f : QSCALE;
#pragma unroll
    for (int mi = 0; mi < 4; ++mi) {
      const int m = bm * 128 + wm * 64 + mi * 16 + l15;   // xn row
      const int bh0 = (m >> 11) * HEADS;
      const int n = m & 2047;
#pragma unroll
      for (int ni = 0; ni < 4; ++ni) {
        const int wc = (colbase & 1023) + ni * 16 + quad * 4;  // q/k col, r-contig
        const int h = wc >> 6, dd = wc & 63;
        f32x4 v = acc[mi][ni] * sc;
        *(u16x4*)&dst[((bh0 + h) * NSEQ + n) * DHEAD + dd] = cvt4(v);
      }
    }
  } else {
    // v blocks: original form -> reg r runs along n -> b64 stores to vt.
    gemm_core128<false>(A, Bt, As, Bs, bm, bn, tid, acc);
    const int colbase = bn * 128 + wn * 64 - 2048;   // v col base, 0..1023
#pragma unroll
    for (int mi = 0; mi < 4; ++mi) {
      const int m0 = bm * 128 + wm * 64 + mi * 16 + quad * 4;   // n, r-contig
      const int bh0 = (m0 >> 11) * HEADS;
      const int n0 = m0 & 2047;
#pragma unroll
      for (int ni = 0; ni < 4; ++ni) {
        const int vcol = colbase + ni * 16 + l15;
        const int h = vcol >> 6, dd = vcol & 63;
        *(u16x4*)&vtb[((bh0 + h) * DHEAD + dd) * NSEQ + n0] = cvt4(acc[mi][ni]);
      }
    }
  }
}

// ---------------- flash attention, transposed-S, fixed-offset softmax.
// block = (bh, 128-row q tile), 4 waves x 32 q rows (2 subtiles of 16);
// per-lane softmax (q = lane&15). Double-buffered K/V staging, ONE barrier
// per kv-iter: next tile's async loads issue right after the barrier and
// complete during compute. p = exp2(s-32); scale cancels in num/denom.
__global__ __launch_bounds__(256, 2) void attn_kernel(
    const unsigned short* __restrict__ qb, const unsigned short* __restrict__ kb,
    const unsigned short* __restrict__ vtb, unsigned short* __restrict__ attn_out) {
  __shared__ __attribute__((aligned(16))) unsigned short Ks[2][64 * 64];   // swizzled
  __shared__ __attribute__((aligned(16))) unsigned short Vts[2][64 * 64];  // swizzled
  __shared__ __attribute__((aligned(16))) unsigned short Ps[4][2][16][72]; // per-wave, per-sub
  const int tid = threadIdx.x, wave = tid >> 6, lane = tid & 63;
  const int l15 = lane & 15, quad = lane >> 4;
  const int bh = blockIdx.x, qt = blockIdx.y;
  const int b = bh >> 4, h = bh & 15;
  const int qbase = qt * 128 + wave * 32;   // this wave's 32 q rows

  // Q fragments (B-operand layout: n=l15=q, k=quad*8+j), q pre-scaled
  bf16x8 aq[2][2];
#pragma unroll
  for (int sub = 0; sub < 2; ++sub) {
    const unsigned short* qrow = qb + (bh * NSEQ + qbase + sub * 16 + l15) * DHEAD;
    aq[sub][0] = as_bf(*(const u16x8*)(qrow + quad * 8));
    aq[sub][1] = as_bf(*(const u16x8*)(qrow + 32 + quad * 8));
  }

  float lsum[2] = {0.f, 0.f};
  f32x4 occ[2][4] = {};   // O^T per sub: d = ct*16+quad*4+r, q = l15

  const int lrow = lane >> 3;
  const int gcol = ((lane & 7) ^ lrow) << 3;
  const unsigned short* Kb = kb  + (bh * NSEQ + wave * 16 + lrow) * DHEAD + gcol;
  const unsigned short* Vb = vtb + (bh * DHEAD + wave * 16 + lrow) * NSEQ + gcol;

  // prologue: stage kv tile 0 into buffer 0
  gl_lds16(Kb,             &Ks[0][(wave * 16) * 64]);
  gl_lds16(Kb + 8 * DHEAD, &Ks[0][(wave * 16 + 8) * 64]);
  gl_lds16(Vb,             &Vts[0][(wave * 16) * 64]);
  gl_lds16(Vb + 8 * NSEQ,  &Vts[0][(wave * 16 + 8) * 64]);

  // the single kv-iter containing this wave's diagonal (both subs share it)
  const int diag_it = qt * 2 + (wave >> 1);

  for (int it = 0; it < NSEQ / 64; ++it) {
    const int cur = it & 1;
    __syncthreads();   // drains this wave's async loads into buf[cur]
    if (it < NSEQ / 64 - 1) {
      const unsigned short* Kn = Kb + (it + 1) * 64 * DHEAD;
      const unsigned short* Vn = Vb + (it + 1) * 64;
      gl_lds16(Kn,             &Ks[cur ^ 1][(wave * 16) * 64]);
      gl_lds16(Kn + 8 * DHEAD, &Ks[cur ^ 1][(wave * 16 + 8) * 64]);
      gl_lds16(Vn,             &Vts[cur ^ 1][(wave * 16) * 64]);
      gl_lds16(Vn + 8 * NSEQ,  &Vts[cur ^ 1][(wave * 16 + 8) * 64]);
    }
    // hoisted fragments, shared by both q-subtiles
    bf16x8 ak[2][4], av[2][4];
#pragma unroll
    for (int kk = 0; kk < 2; ++kk)
#pragma unroll
      for (int ct = 0; ct < 4; ++ct) {
        ak[kk][ct] = lds_frag(&Ks[cur][0],  ct * 16 + l15, kk * 4 + quad);
        av[kk][ct] = lds_frag(&Vts[cur][0], ct * 16 + l15, kk * 4 + quad);
      }
#pragma unroll
    for (int sub = 0; sub < 2; ++sub) {
      // S^T - 32 : col=l15=q, row=quad*4+r=kv offset (per ct tile of 16)
      f32x4 scc[4];
#pragma unroll
      for (int ct = 0; ct < 4; ++ct) scc[ct] = (f32x4){-32.f, -32.f, -32.f, -32.f};
#pragma unroll
      for (int kk = 0; kk < 2; ++kk)
#pragma unroll
        for (int ct = 0; ct < 4; ++ct)
          scc[ct] = __builtin_amdgcn_mfma_f32_16x16x32_bf16(ak[kk][ct], aq[sub][kk], scc[ct], 0, 0, 0);
#pragma unroll
      for (int ct = 0; ct < 4; ++ct)
#pragma unroll
        for (int r = 0; r < 4; ++r) scc[ct][r] = EXP2(scc[ct][r]);

      // diagonal mask (wave-uniform branch; zero BEFORE summing)
      if (it == diag_it) {
        const int kvo_want = (wave & 1) * 32 + sub * 16 + l15;
#pragma unroll
        for (int ct = 0; ct < 4; ++ct)
#pragma unroll
          for (int r = 0; r < 4; ++r)
            if (ct * 16 + quad * 4 + r == kvo_want) scc[ct][r] = 0.f;
      }

      f32x4 ps4 = (scc[0] + scc[1]) + (scc[2] + scc[3]);
      lsum[sub] += (ps4[0] + ps4[1]) + (ps4[2] + ps4[3]);

      // P[q][kv] -> LDS (wave-private slice, same-wave in-order)
#pragma unroll
      for (int ct = 0; ct < 4; ++ct)
        *(u16x4*)&Ps[wave][sub][l15][ct * 16 + quad * 4] = cvt4(scc[ct]);

      // O^T += V^T P^T : A=Vt (m=d,k=kv), B=P (n=q,k=kv)
#pragma unroll
      for (int kk = 0; kk < 2; ++kk) {
        bf16x8 bp = as_bf(*(const u16x8*)&Ps[wave][sub][l15][kk * 32 + quad * 8]);
#pragma unroll
        for (int ct = 0; ct < 4; ++ct)
          occ[sub][ct] = __builtin_amdgcn_mfma_f32_16x16x32_bf16(av[kk][ct], bp, occ[sub][ct], 0, 0, 0);
      }
    }
  }
  // epilogue: O^T / l -> attn_out[b*N + q][h*64 + d], d-contiguous 8B stores
#pragma unroll
  for (int sub = 0; sub < 2; ++sub) {
    float l = lsum[sub];
    l += __shfl_xor(l, 16);
    l += __shfl_xor(l, 32);
    const float rl = __builtin_amdgcn_rcpf(l);
    const int qg = qbase + sub * 16 + l15;
#pragma unroll
    for (int ct = 0; ct < 4; ++ct) {
      f32x4 ov = occ[sub][ct] * rl;
      *(u16x4*)&attn_out[(b * NSEQ + qg) * DIMM + h * DHEAD + ct * 16 + quad * 4] = cvt4(ov);
    }
  }
}

// ---------------- output projection (C^T): [4096,1024] @ woutT[1024,1024] -> fp32
__global__ __launch_bounds__(256, 2) void gemm_out_kernel(
    const unsigned short* __restrict__ A,   // attn bf16 [4096,1024]
    const unsigned short* __restrict__ Bt,  // woutT bf16 [1024,1024]
    float* __restrict__ out) {
  __shared__ __attribute__((aligned(16))) unsigned short As[128 * 64];
  __shared__ __attribute__((aligned(16))) unsigned short Bs[128 * 64];
  const int tid = threadIdx.x;
  const int bm = blockIdx.y, bn = blockIdx.x;
  f32x4 acc[4][4] = {};
  gemm_core128<true>(A, Bt, As, Bs, bm, bn, tid, acc);

  const int lane = tid & 63, wave = tid >> 6;
  const int l15 = lane & 15, quad = lane >> 4;
  const int wm = wave >> 1, wn = wave & 1;
#pragma unroll
  for (int mi = 0; mi < 4; ++mi) {
    const int m = bm * 128 + wm * 64 + mi * 16 + l15;   // attn row
#pragma unroll
    for (int ni = 0; ni < 4; ++ni) {
      const int col = bn * 128 + wn * 64 + ni * 16 + quad * 4;  // r-contig
      *(f32x4*)&out[m * DIMM + col] = acc[mi][ni];
    }
  }
}

extern "C" void kernel_launch(void* const* d_in, const int* in_sizes, int n_in,
                              void* d_out, int out_size, void* d_ws, size_t ws_size,
                              hipStream_t stream) {
  const float* x     = (const float*)d_in[0];
  const float* gamma = (const float*)d_in[1];
  const float* beta  = (const float*)d_in[2];
  const float* w_qkv = (const float*)d_in[3];  // [1024, 3072]
  const float* w_out = (const float*)d_in[4];  // [1024, 1024]
  float* out = (float*)d_out;

  char* ws = (char*)d_ws;
  unsigned short* xn    = (unsigned short*)(ws);                        // 8 MB
  unsigned short* wqkvT = (unsigned short*)(ws + 8388608);              // 6 MB
  unsigned short* woutT = (unsigned short*)(ws + 14680064);             // 2 MB
  unsigned short* qbuf  = (unsigned short*)(ws + 16777216);             // 8 MB
  unsigned short* kbuf  = (unsigned short*)(ws + 25165824);             // 8 MB
  unsigned short* vtbuf = (unsigned short*)(ws + 33554432);             // 8 MB
  unsigned short* attnb = (unsigned short*)(ws + 41943040);             // 8 MB

  transpose2_kernel<<<dim3((QKVN + DIMM) / 32, DIMM / 32), 256, 0, stream>>>(w_qkv, w_out, wqkvT, woutT);
  ln_kernel<<<MROWS, 256, 0, stream>>>(x, gamma, beta, xn);
  gemm_qkv_kernel<<<dim3(24, MROWS / 128), 256, 0, stream>>>(xn, wqkvT, qbuf, kbuf, vtbuf);
  attn_kernel<<<dim3(BATCH * HEADS, NSEQ / 128), 256, 0, stream>>>(qbuf, kbuf, vtbuf, attnb);
  gemm_out_kernel<<<dim3(DIMM / 128, MROWS / 128), 256, 0, stream>>>(attnb, woutT, out);
}

// Round 5
// 188.094 us; speedup vs baseline: 1.7317x; 1.0063x over previous
//
#include <hip/hip_runtime.h>

// Fused: LayerNorm -> QKV proj -> per-head attention (diag masked) -> out proj
// B=2, N=2048, D=1024, H=16, dh=64. bf16 MFMA 16x16x32 everywhere.
// R5: single-barrier double-buffered K-loops in BOTH gemms (attention-style
//     async pipeline); gemm_out retiled to M64xN128 (grid 512, was 256);
//     LN + weight transposes merged into one prep kernel (4 launches).

#define DIMM   1024
#define NSEQ   2048
#define BATCH  2
#define HEADS  16
#define DHEAD  64
#define QKVN   3072
#define MROWS  4096   // BATCH*NSEQ

typedef float          f32x4  __attribute__((ext_vector_type(4)));
typedef __bf16         bf16x8 __attribute__((ext_vector_type(8)));
typedef __bf16         bf16x4 __attribute__((ext_vector_type(4)));
typedef unsigned short u16x8  __attribute__((ext_vector_type(8)));
typedef unsigned short u16x4  __attribute__((ext_vector_type(4)));

// SCALE * log2(e): fold into q so softmax uses exp2 directly.
#define QSCALE (0.125f * 1.4426950408889634f)

#if __has_builtin(__builtin_amdgcn_exp2f)
#define EXP2(x) __builtin_amdgcn_exp2f(x)
#else
#define EXP2(x) exp2f(x)
#endif

__device__ __forceinline__ unsigned short f2bf(float f) {
  unsigned u = __builtin_bit_cast(unsigned, f);
  u += 0x7FFFu + ((u >> 16) & 1u);   // round-to-nearest-even
  return (unsigned short)(u >> 16);
}
__device__ __forceinline__ bf16x8 as_bf(u16x8 v) { return __builtin_bit_cast(bf16x8, v); }

// f32x4 -> 4 bf16 (RNE)
__device__ __forceinline__ u16x4 cvt4(f32x4 v) {
  bf16x4 b;
  b[0] = (__bf16)v[0]; b[1] = (__bf16)v[1]; b[2] = (__bf16)v[2]; b[3] = (__bf16)v[3];
  return __builtin_bit_cast(u16x4, b);
}

// async global->LDS, 16B per lane; LDS dest = wave-uniform base + lane*16
__device__ __forceinline__ void gl_lds16(const unsigned short* g, unsigned short* l) {
  __builtin_amdgcn_global_load_lds(
      (const __attribute__((address_space(1))) unsigned*)g,
      (__attribute__((address_space(3))) unsigned*)l, 16, 0, 0);
}

// swizzled b128 fragment read from an unpadded [rows][64] bf16 tile:
// LDS chunk c at row r holds global chunk c ^ (r&7).
__device__ __forceinline__ bf16x8 lds_frag(const unsigned short* base, int row, int chunk) {
  return as_bf(*(const u16x8*)&base[row * 64 + ((chunk ^ (row & 7)) << 3)]);
}

// ---------------- weight transpose tile + fp32->bf16: dst[c][r] = src[r][c]
__device__ __forceinline__ void transpose_tile(
    const float* __restrict__ src, unsigned short* __restrict__ dst,
    int R, int C, int bx, int by, int tid) {
  __shared__ float t[32][33];
  const int rb = by * 32, cb = bx * 32;
  const int r0 = tid >> 5;   // 0..7
  const int c  = tid & 31;
#pragma unroll
  for (int i = 0; i < 4; ++i)
    t[r0 + i * 8][c] = src[(rb + r0 + i * 8) * C + cb + c];
  __syncthreads();
#pragma unroll
  for (int i = 0; i < 4; ++i)
    dst[(cb + r0 + i * 8) * R + rb + c] = f2bf(t[c][r0 + i * 8]);
}

// ---------------- prep: LN (blocks 0..4095) + weight transposes (4096..8191)
__global__ __launch_bounds__(256) void prep_kernel(
    const float* __restrict__ x, const float* __restrict__ g,
    const float* __restrict__ be, const float* __restrict__ w_qkv,
    const float* __restrict__ w_out, unsigned short* __restrict__ xn,
    unsigned short* __restrict__ wqkvT, unsigned short* __restrict__ woutT) {
  const int bid = blockIdx.x, tid = threadIdx.x;
  if (bid < MROWS) {
    // LayerNorm: one row (1024) per 256-thread block, bf16 out
    const int row = bid;
    const int wave = tid >> 6, lane = tid & 63;
    const float4 v = *(const float4*)&x[row * DIMM + tid * 4];
    float s  = v.x + v.y + v.z + v.w;
    float s2 = v.x * v.x + v.y * v.y + v.z * v.z + v.w * v.w;
#pragma unroll
    for (int o = 32; o >= 1; o >>= 1) { s += __shfl_xor(s, o); s2 += __shfl_xor(s2, o); }
    __shared__ float ps[4], ps2[4];
    if (lane == 0) { ps[wave] = s; ps2[wave] = s2; }
    __syncthreads();
    s  = ps[0] + ps[1] + ps[2] + ps[3];
    s2 = ps2[0] + ps2[1] + ps2[2] + ps2[3];
    const float mu  = s * (1.0f / DIMM);
    const float var = s2 * (1.0f / DIMM) - mu * mu;
    const float rs  = rsqrtf(var + 1e-5f);
    const float4 gg = *(const float4*)&g[tid * 4];
    const float4 bb = *(const float4*)&be[tid * 4];
    u16x4 o;
    o[0] = f2bf((v.x - mu) * rs * gg.x + bb.x);
    o[1] = f2bf((v.y - mu) * rs * gg.y + bb.y);
    o[2] = f2bf((v.z - mu) * rs * gg.z + bb.z);
    o[3] = f2bf((v.w - mu) * rs * gg.w + bb.w);
    *(u16x4*)&xn[row * DIMM + tid * 4] = o;
  } else {
    const int t = bid - MROWS;            // 0..4095
    const int bx = t & 127, by = t >> 7;  // 128 x 32
    if (bx < QKVN / 32) transpose_tile(w_qkv, wqkvT, DIMM, QKVN, bx, by, tid);
    else                transpose_tile(w_out, woutT, DIMM, DIMM, bx - QKVN / 32, by, tid);
  }
}

// ---------------- merged QKV GEMM: 128x128 tiles, double-buffered single-barrier
// K-loop. bn 0..15 -> q/k (C^T orientation), bn 16..23 -> v (C orientation).
__global__ __launch_bounds__(256, 2) void gemm_qkv_kernel(
    const unsigned short* __restrict__ A, const unsigned short* __restrict__ Bt,
    unsigned short* __restrict__ qb, unsigned short* __restrict__ kb,
    unsigned short* __restrict__ vtb) {
  __shared__ __attribute__((aligned(16))) unsigned short As[2 * 128 * 64];  // 32 KB
  __shared__ __attribute__((aligned(16))) unsigned short Bs[2 * 128 * 64];  // 32 KB
  const int tid = threadIdx.x;
  const int bm = blockIdx.y, bn = blockIdx.x;
  const int lane = tid & 63, wave = tid >> 6;
  const int l15 = lane & 15, quad = lane >> 4;
  const int wm = wave >> 1, wn = wave & 1;
  const int lrow = lane >> 3;
  const int gcol = ((lane & 7) ^ lrow) << 3;
  const unsigned short* Ab = A  + (bm * 128 + wave * 32 + lrow) * DIMM + gcol;
  const unsigned short* Bb = Bt + (bn * 128 + wave * 32 + lrow) * DIMM + gcol;
  const bool swap = (bn < 16);
  f32x4 acc[4][4] = {};

  // prologue: stage k-tile 0 into buffer 0
#pragma unroll
  for (int j = 0; j < 4; ++j) {
    gl_lds16(Ab + j * 8 * DIMM, &As[(wave * 32 + j * 8) * 64]);
    gl_lds16(Bb + j * 8 * DIMM, &Bs[(wave * 32 + j * 8) * 64]);
  }
  for (int it = 0; it < DIMM / 64; ++it) {
    const int cur = it & 1;
    __syncthreads();   // per-wave vmcnt(0) drain -> buf[cur] complete for all
    if (it < DIMM / 64 - 1) {
      const int k0 = (it + 1) * 64;
      unsigned short* An = &As[(cur ^ 1) * 8192];
      unsigned short* Bn = &Bs[(cur ^ 1) * 8192];
#pragma unroll
      for (int j = 0; j < 4; ++j) {
        gl_lds16(Ab + j * 8 * DIMM + k0, &An[(wave * 32 + j * 8) * 64]);
        gl_lds16(Bb + j * 8 * DIMM + k0, &Bn[(wave * 32 + j * 8) * 64]);
      }
    }
    const unsigned short* Ac = &As[cur * 8192];
    const unsigned short* Bc = &Bs[cur * 8192];
#pragma unroll
    for (int kk = 0; kk < 2; ++kk) {
      bf16x8 af[4], bfr[4];
#pragma unroll
      for (int mi = 0; mi < 4; ++mi) af[mi]  = lds_frag(Ac, wm * 64 + mi * 16 + l15, kk * 4 + quad);
#pragma unroll
      for (int ni = 0; ni < 4; ++ni) bfr[ni] = lds_frag(Bc, wn * 64 + ni * 16 + l15, kk * 4 + quad);
      if (swap) {
#pragma unroll
        for (int mi = 0; mi < 4; ++mi)
#pragma unroll
          for (int ni = 0; ni < 4; ++ni)
            acc[mi][ni] = __builtin_amdgcn_mfma_f32_16x16x32_bf16(bfr[ni], af[mi], acc[mi][ni], 0, 0, 0);
      } else {
#pragma unroll
        for (int mi = 0; mi < 4; ++mi)
#pragma unroll
          for (int ni = 0; ni < 4; ++ni)
            acc[mi][ni] = __builtin_amdgcn_mfma_f32_16x16x32_bf16(af[mi], bfr[ni], acc[mi][ni], 0, 0, 0);
      }
    }
  }

  if (swap) {
    // q/k blocks: C^T -> reg r runs along weight col (dd) -> b64 stores.
    const int colbase = bn * 128 + wn * 64;        // wave-uniform
    const int which = colbase >> 10;               // 0=q, 1=k
    unsigned short* dst = which ? kb : qb;
    const float sc = which ? 1.0f : QSCALE;
#pragma unroll
    for (int mi = 0; mi < 4; ++mi) {
      const int m = bm * 128 + wm * 64 + mi * 16 + l15;   // xn row
      const int bh0 = (m >> 11) * HEADS;
      const int n = m & 2047;
#pragma unroll
      for (int ni = 0; ni < 4; ++ni) {
        const int wc = (colbase & 1023) + ni * 16 + quad * 4;  // r-contig
        const int h = wc >> 6, dd = wc & 63;
        f32x4 v = acc[mi][ni] * sc;
        *(u16x4*)&dst[((bh0 + h) * NSEQ + n) * DHEAD + dd] = cvt4(v);
      }
    }
  } else {
    // v blocks: C -> reg r runs along n -> b64 stores to vt.
    const int colbase = bn * 128 + wn * 64 - 2048;   // v col base, 0..1023
#pragma unroll
    for (int mi = 0; mi < 4; ++mi) {
      const int m0 = bm * 128 + wm * 64 + mi * 16 + quad * 4;   // n, r-contig
      const int bh0 = (m0 >> 11) * HEADS;
      const int n0 = m0 & 2047;
#pragma unroll
      for (int ni = 0; ni < 4; ++ni) {
        const int vcol = colbase + ni * 16 + l15;
        const int h = vcol >> 6, dd = vcol & 63;
        *(u16x4*)&vtb[((bh0 + h) * DHEAD + dd) * NSEQ + n0] = cvt4(acc[mi][ni]);
      }
    }
  }
}

// ---------------- flash attention, transposed-S, fixed-offset softmax.
// block = (bh, 128-row q tile), 4 waves x 32 q rows (2 subtiles of 16);
// per-lane softmax (q = lane&15). Double-buffered K/V staging, ONE barrier
// per kv-iter. p = exp2(s-32); scale cancels in num/denom.
__global__ __launch_bounds__(256, 2) void attn_kernel(
    const unsigned short* __restrict__ qb, const unsigned short* __restrict__ kb,
    const unsigned short* __restrict__ vtb, unsigned short* __restrict__ attn_out) {
  __shared__ __attribute__((aligned(16))) unsigned short Ks[2][64 * 64];   // swizzled
  __shared__ __attribute__((aligned(16))) unsigned short Vts[2][64 * 64];  // swizzled
  __shared__ __attribute__((aligned(16))) unsigned short Ps[4][2][16][72]; // per-wave, per-sub
  const int tid = threadIdx.x, wave = tid >> 6, lane = tid & 63;
  const int l15 = lane & 15, quad = lane >> 4;
  const int bh = blockIdx.x, qt = blockIdx.y;
  const int b = bh >> 4, h = bh & 15;
  const int qbase = qt * 128 + wave * 32;   // this wave's 32 q rows

  // Q fragments (B-operand layout: n=l15=q, k=quad*8+j), q pre-scaled
  bf16x8 aq[2][2];
#pragma unroll
  for (int sub = 0; sub < 2; ++sub) {
    const unsigned short* qrow = qb + (bh * NSEQ + qbase + sub * 16 + l15) * DHEAD;
    aq[sub][0] = as_bf(*(const u16x8*)(qrow + quad * 8));
    aq[sub][1] = as_bf(*(const u16x8*)(qrow + 32 + quad * 8));
  }

  float lsum[2] = {0.f, 0.f};
  f32x4 occ[2][4] = {};   // O^T per sub: d = ct*16+quad*4+r, q = l15

  const int lrow = lane >> 3;
  const int gcol = ((lane & 7) ^ lrow) << 3;
  const unsigned short* Kb = kb  + (bh * NSEQ + wave * 16 + lrow) * DHEAD + gcol;
  const unsigned short* Vb = vtb + (bh * DHEAD + wave * 16 + lrow) * NSEQ + gcol;

  // prologue: stage kv tile 0 into buffer 0
  gl_lds16(Kb,             &Ks[0][(wave * 16) * 64]);
  gl_lds16(Kb + 8 * DHEAD, &Ks[0][(wave * 16 + 8) * 64]);
  gl_lds16(Vb,             &Vts[0][(wave * 16) * 64]);
  gl_lds16(Vb + 8 * NSEQ,  &Vts[0][(wave * 16 + 8) * 64]);

  // the single kv-iter containing this wave's diagonal (both subs share it)
  const int diag_it = qt * 2 + (wave >> 1);

  for (int it = 0; it < NSEQ / 64; ++it) {
    const int cur = it & 1;
    __syncthreads();   // drains this wave's async loads into buf[cur]
    if (it < NSEQ / 64 - 1) {
      const unsigned short* Kn = Kb + (it + 1) * 64 * DHEAD;
      const unsigned short* Vn = Vb + (it + 1) * 64;
      gl_lds16(Kn,             &Ks[cur ^ 1][(wave * 16) * 64]);
      gl_lds16(Kn + 8 * DHEAD, &Ks[cur ^ 1][(wave * 16 + 8) * 64]);
      gl_lds16(Vn,             &Vts[cur ^ 1][(wave * 16) * 64]);
      gl_lds16(Vn + 8 * NSEQ,  &Vts[cur ^ 1][(wave * 16 + 8) * 64]);
    }
    // hoisted fragments, shared by both q-subtiles
    bf16x8 ak[2][4], av[2][4];
#pragma unroll
    for (int kk = 0; kk < 2; ++kk)
#pragma unroll
      for (int ct = 0; ct < 4; ++ct) {
        ak[kk][ct] = lds_frag(&Ks[cur][0],  ct * 16 + l15, kk * 4 + quad);
        av[kk][ct] = lds_frag(&Vts[cur][0], ct * 16 + l15, kk * 4 + quad);
      }
#pragma unroll
    for (int sub = 0; sub < 2; ++sub) {
      // S^T - 32 : col=l15=q, row=quad*4+r=kv offset (per ct tile of 16)
      f32x4 scc[4];
#pragma unroll
      for (int ct = 0; ct < 4; ++ct) scc[ct] = (f32x4){-32.f, -32.f, -32.f, -32.f};
#pragma unroll
      for (int kk = 0; kk < 2; ++kk)
#pragma unroll
        for (int ct = 0; ct < 4; ++ct)
          scc[ct] = __builtin_amdgcn_mfma_f32_16x16x32_bf16(ak[kk][ct], aq[sub][kk], scc[ct], 0, 0, 0);
#pragma unroll
      for (int ct = 0; ct < 4; ++ct)
#pragma unroll
        for (int r = 0; r < 4; ++r) scc[ct][r] = EXP2(scc[ct][r]);

      // diagonal mask (wave-uniform branch; zero BEFORE summing)
      if (it == diag_it) {
        const int kvo_want = (wave & 1) * 32 + sub * 16 + l15;
#pragma unroll
        for (int ct = 0; ct < 4; ++ct)
#pragma unroll
          for (int r = 0; r < 4; ++r)
            if (ct * 16 + quad * 4 + r == kvo_want) scc[ct][r] = 0.f;
      }

      f32x4 ps4 = (scc[0] + scc[1]) + (scc[2] + scc[3]);
      lsum[sub] += (ps4[0] + ps4[1]) + (ps4[2] + ps4[3]);

      // P[q][kv] -> LDS (wave-private slice, same-wave in-order)
#pragma unroll
      for (int ct = 0; ct < 4; ++ct)
        *(u16x4*)&Ps[wave][sub][l15][ct * 16 + quad * 4] = cvt4(scc[ct]);

      // O^T += V^T P^T : A=Vt (m=d,k=kv), B=P (n=q,k=kv)
#pragma unroll
      for (int kk = 0; kk < 2; ++kk) {
        bf16x8 bp = as_bf(*(const u16x8*)&Ps[wave][sub][l15][kk * 32 + quad * 8]);
#pragma unroll
        for (int ct = 0; ct < 4; ++ct)
          occ[sub][ct] = __builtin_amdgcn_mfma_f32_16x16x32_bf16(av[kk][ct], bp, occ[sub][ct], 0, 0, 0);
      }
    }
  }
  // epilogue: O^T / l -> attn_out[b*N + q][h*64 + d], d-contiguous 8B stores
#pragma unroll
  for (int sub = 0; sub < 2; ++sub) {
    float l = lsum[sub];
    l += __shfl_xor(l, 16);
    l += __shfl_xor(l, 32);
    const float rl = __builtin_amdgcn_rcpf(l);
    const int qg = qbase + sub * 16 + l15;
#pragma unroll
    for (int ct = 0; ct < 4; ++ct) {
      f32x4 ov = occ[sub][ct] * rl;
      *(u16x4*)&attn_out[(b * NSEQ + qg) * DIMM + h * DHEAD + ct * 16 + quad * 4] = cvt4(ov);
    }
  }
}

// ---------------- output projection (C^T): [4096,1024] @ woutT[1024,1024] -> fp32
// M64 x N128 tiles -> grid (8,64)=512 blocks; double-buffered single-barrier K.
__global__ __launch_bounds__(256, 2) void gemm_out_kernel(
    const unsigned short* __restrict__ A,   // attn bf16 [4096,1024]
    const unsigned short* __restrict__ Bt,  // woutT bf16 [1024,1024]
    float* __restrict__ out) {
  __shared__ __attribute__((aligned(16))) unsigned short As[2 * 64 * 64];   // 16 KB
  __shared__ __attribute__((aligned(16))) unsigned short Bs[2 * 128 * 64];  // 32 KB
  const int tid = threadIdx.x;
  const int bm = blockIdx.y, bn = blockIdx.x;
  const int lane = tid & 63, wave = tid >> 6;
  const int l15 = lane & 15, quad = lane >> 4;
  const int wm = wave >> 1, wn = wave & 1;
  const int lrow = lane >> 3;
  const int gcol = ((lane & 7) ^ lrow) << 3;
  const unsigned short* Ab = A  + (bm * 64 + wave * 16 + lrow) * DIMM + gcol;
  const unsigned short* Bb = Bt + (bn * 128 + wave * 32 + lrow) * DIMM + gcol;
  f32x4 acc[2][4] = {};

  // prologue: stage k-tile 0 into buffer 0
#pragma unroll
  for (int j = 0; j < 2; ++j) gl_lds16(Ab + j * 8 * DIMM, &As[(wave * 16 + j * 8) * 64]);
#pragma unroll
  for (int j = 0; j < 4; ++j) gl_lds16(Bb + j * 8 * DIMM, &Bs[(wave * 32 + j * 8) * 64]);

  for (int it = 0; it < DIMM / 64; ++it) {
    const int cur = it & 1;
    __syncthreads();
    if (it < DIMM / 64 - 1) {
      const int k0 = (it + 1) * 64;
      unsigned short* An = &As[(cur ^ 1) * 4096];
      unsigned short* Bn = &Bs[(cur ^ 1) * 8192];
#pragma unroll
      for (int j = 0; j < 2; ++j) gl_lds16(Ab + j * 8 * DIMM + k0, &An[(wave * 16 + j * 8) * 64]);
#pragma unroll
      for (int j = 0; j < 4; ++j) gl_lds16(Bb + j * 8 * DIMM + k0, &Bn[(wave * 32 + j * 8) * 64]);
    }
    const unsigned short* Ac = &As[cur * 4096];
    const unsigned short* Bc = &Bs[cur * 8192];
#pragma unroll
    for (int kk = 0; kk < 2; ++kk) {
      bf16x8 af[2], bfr[4];
#pragma unroll
      for (int mi = 0; mi < 2; ++mi) af[mi]  = lds_frag(Ac, wm * 32 + mi * 16 + l15, kk * 4 + quad);
#pragma unroll
      for (int ni = 0; ni < 4; ++ni) bfr[ni] = lds_frag(Bc, wn * 64 + ni * 16 + l15, kk * 4 + quad);
#pragma unroll
      for (int mi = 0; mi < 2; ++mi)
#pragma unroll
        for (int ni = 0; ni < 4; ++ni)
          acc[mi][ni] = __builtin_amdgcn_mfma_f32_16x16x32_bf16(bfr[ni], af[mi], acc[mi][ni], 0, 0, 0);
    }
  }
  // C^T epilogue: col=l15 -> out row m; row(quad*4+r, r-contig) -> out col.
#pragma unroll
  for (int mi = 0; mi < 2; ++mi) {
    const int m = bm * 64 + wm * 32 + mi * 16 + l15;   // attn row
#pragma unroll
    for (int ni = 0; ni < 4; ++ni) {
      const int col = bn * 128 + wn * 64 + ni * 16 + quad * 4;  // r-contig
      *(f32x4*)&out[m * DIMM + col] = acc[mi][ni];
    }
  }
}

extern "C" void kernel_launch(void* const* d_in, const int* in_sizes, int n_in,
                              void* d_out, int out_size, void* d_ws, size_t ws_size,
                              hipStream_t stream) {
  const float* x     = (const float*)d_in[0];
  const float* gamma = (const float*)d_in[1];
  const float* beta  = (const float*)d_in[2];
  const float* w_qkv = (const float*)d_in[3];  // [1024, 3072]
  const float* w_out = (const float*)d_in[4];  // [1024, 1024]
  float* out = (float*)d_out;

  char* ws = (char*)d_ws;
  unsigned short* xn    = (unsigned short*)(ws);                        // 8 MB
  unsigned short* wqkvT = (unsigned short*)(ws + 8388608);              // 6 MB
  unsigned short* woutT = (unsigned short*)(ws + 14680064);             // 2 MB
  unsigned short* qbuf  = (unsigned short*)(ws + 16777216);             // 8 MB
  unsigned short* kbuf  = (unsigned short*)(ws + 25165824);             // 8 MB
  unsigned short* vtbuf = (unsigned short*)(ws + 33554432);             // 8 MB
  unsigned short* attnb = (unsigned short*)(ws + 41943040);             // 8 MB

  prep_kernel<<<MROWS + (QKVN + DIMM) / 32 * (DIMM / 32), 256, 0, stream>>>(
      x, gamma, beta, w_qkv, w_out, xn, wqkvT, woutT);
  gemm_qkv_kernel<<<dim3(24, MROWS / 128), 256, 0, stream>>>(xn, wqkvT, qbuf, kbuf, vtbuf);
  attn_kernel<<<dim3(BATCH * HEADS, NSEQ / 128), 256, 0, stream>>>(qbuf, kbuf, vtbuf, attnb);
  gemm_out_kernel<<<dim3(DIMM / 128, MROWS / 64), 256, 0, stream>>>(attnb, woutT, out);
}